// Round 9
// baseline (375.461 us; speedup 1.0000x reference)
//
#include <hip/hip_runtime.h>
#include <hip/hip_bf16.h>
#include <hip/hip_cooperative_groups.h>
#include <cmath>

namespace cg = cooperative_groups;

// ---------------------------------------------------------------------------
// Mamba block, round 9: launch-count reduction.
//   prep_all -> gemm1 -> conv_silu -> gemm3 -> rates_fused(+reduce)
//   -> scan3 (cooperative: states + stitch + out) -> gemm2        (7 launches)
//   B=2, L=2048, D_MODEL=512, D_INNER=1024, D_STATE=16, D_CONV=4, EPS=1e-8
// ---------------------------------------------------------------------------

#define L_SEQ 2048
#define NBATCH 2
#define DI 1024
#define NC 64
#define LC 32
#define EPS_F 1e-8f
#define LOG_EPS -18.420680744f

typedef __attribute__((ext_vector_type(8))) __bf16 bf16x8;
typedef __attribute__((ext_vector_type(4))) float f32x4;

__device__ __forceinline__ float silu_f(float v) {
    return v / (1.f + __expf(-v));
}

__device__ __forceinline__ ushort bf16_bits(float v) {
    __hip_bfloat16 h = __float2bfloat16(v);
    return *reinterpret_cast<ushort*>(&h);
}

__device__ __forceinline__ float bf2f(ushort u) {
    union { unsigned u; float f; } c;
    c.u = ((unsigned)u) << 16;
    return c.f;
}

// ---------------- GEMM1: [xinb | resb] = x @ W_in^T + b (bf16 out) ---------
__global__ __launch_bounds__(256) void gemm1_mfma(
    const ushort* __restrict__ A, const ushort* __restrict__ Bt,
    const float* __restrict__ bias, ushort* __restrict__ C0,
    ushort* __restrict__ C1, int M, int N, int K)
{
    __shared__ ushort lA[128 * 64];
    __shared__ ushort lB[128 * 64];
    const int tid = threadIdx.x;
    const int w = tid >> 6, ln = tid & 63;
    const int wr = w >> 1, wc = w & 1;
    const int bm = blockIdx.y * 128, bn = blockIdx.x * 128;
    const int q = ln >> 4, r = ln & 15;
    f32x4 acc[4][4] = {};

    for (int k0 = 0; k0 < K; k0 += 64) {
        #pragma unroll
        for (int j = 0; j < 4; ++j) {
            int i = (w * 4 + j) * 64 + ln;
            int m = i >> 3, k8 = (i & 7) * 8;
            __builtin_amdgcn_global_load_lds(
                (const __attribute__((address_space(1))) void*)(A + (size_t)(bm + m) * K + k0 + k8),
                (__attribute__((address_space(3))) void*)(lA + (size_t)i * 8),
                16, 0, 0);
            __builtin_amdgcn_global_load_lds(
                (const __attribute__((address_space(1))) void*)(Bt + (size_t)(bn + m) * K + k0 + k8),
                (__attribute__((address_space(3))) void*)(lB + (size_t)i * 8),
                16, 0, 0);
        }
        __syncthreads();
        #pragma unroll
        for (int kk = 0; kk < 2; ++kk) {
            const int ko = kk * 32 + q * 8;
            bf16x8 af[4], bfr[4];
            #pragma unroll
            for (int m = 0; m < 4; ++m)
                af[m] = *reinterpret_cast<const bf16x8*>(&lA[(wr * 64 + m * 16 + r) * 64 + ko]);
            #pragma unroll
            for (int n = 0; n < 4; ++n)
                bfr[n] = *reinterpret_cast<const bf16x8*>(&lB[(wc * 64 + n * 16 + r) * 64 + ko]);
            #pragma unroll
            for (int m = 0; m < 4; ++m)
                #pragma unroll
                for (int n = 0; n < 4; ++n)
                    acc[m][n] = __builtin_amdgcn_mfma_f32_16x16x32_bf16(af[m], bfr[n], acc[m][n], 0, 0, 0);
        }
        __syncthreads();
    }

    const bool lo = (bn < 1024);
    #pragma unroll
    for (int n = 0; n < 4; ++n) {
        int col = bn + wc * 64 + n * 16 + r;
        float bv = bias[col];
        #pragma unroll
        for (int m = 0; m < 4; ++m) {
            int row0 = bm + wr * 64 + m * 16 + q * 4;
            #pragma unroll
            for (int j = 0; j < 4; ++j) {
                ushort v = bf16_bits(acc[m][n][j] + bv);
                if (lo) C0[(size_t)(row0 + j) * 1024 + col] = v;
                else    C1[(size_t)(row0 + j) * 1024 + (col - 1024)] = v;
            }
        }
    }
}

// ---------------- GEMM2: out = ybf @ Wt2^T + b (f32 out, 128x64 tile) ------
__global__ __launch_bounds__(256) void gemm2_mfma(
    const ushort* __restrict__ A, const ushort* __restrict__ Bt,
    const float* __restrict__ bias, float* __restrict__ C,
    int M, int N, int K)
{
    __shared__ ushort lA[128 * 64];
    __shared__ ushort lB[64 * 64];
    const int tid = threadIdx.x;
    const int w = tid >> 6, ln = tid & 63;
    const int wr = w >> 1, wc = w & 1;
    const int bm = blockIdx.y * 128, bn = blockIdx.x * 64;
    const int q = ln >> 4, r = ln & 15;
    f32x4 acc[4][2] = {};

    for (int k0 = 0; k0 < K; k0 += 64) {
        #pragma unroll
        for (int j = 0; j < 4; ++j) {
            int i = (w * 4 + j) * 64 + ln;
            int m = i >> 3, k8 = (i & 7) * 8;
            __builtin_amdgcn_global_load_lds(
                (const __attribute__((address_space(1))) void*)(A + (size_t)(bm + m) * K + k0 + k8),
                (__attribute__((address_space(3))) void*)(lA + (size_t)i * 8),
                16, 0, 0);
        }
        #pragma unroll
        for (int j = 0; j < 2; ++j) {
            int i = (w * 2 + j) * 64 + ln;
            int m = i >> 3, k8 = (i & 7) * 8;
            __builtin_amdgcn_global_load_lds(
                (const __attribute__((address_space(1))) void*)(Bt + (size_t)(bn + m) * K + k0 + k8),
                (__attribute__((address_space(3))) void*)(lB + (size_t)i * 8),
                16, 0, 0);
        }
        __syncthreads();
        #pragma unroll
        for (int kk = 0; kk < 2; ++kk) {
            const int ko = kk * 32 + q * 8;
            bf16x8 af[4], bfr[2];
            #pragma unroll
            for (int m = 0; m < 4; ++m)
                af[m] = *reinterpret_cast<const bf16x8*>(&lA[(wr * 64 + m * 16 + r) * 64 + ko]);
            #pragma unroll
            for (int n = 0; n < 2; ++n)
                bfr[n] = *reinterpret_cast<const bf16x8*>(&lB[(wc * 32 + n * 16 + r) * 64 + ko]);
            #pragma unroll
            for (int m = 0; m < 4; ++m)
                #pragma unroll
                for (int n = 0; n < 2; ++n)
                    acc[m][n] = __builtin_amdgcn_mfma_f32_16x16x32_bf16(af[m], bfr[n], acc[m][n], 0, 0, 0);
        }
        __syncthreads();
    }

    #pragma unroll
    for (int n = 0; n < 2; ++n) {
        int col = bn + wc * 32 + n * 16 + r;
        float bv = bias[col];
        #pragma unroll
        for (int m = 0; m < 4; ++m) {
            int row0 = bm + wr * 64 + m * 16 + q * 4;
            #pragma unroll
            for (int j = 0; j < 4; ++j)
                C[(size_t)(row0 + j) * N + col] = acc[m][n][j] + bv;
        }
    }
}

// ---------------- GEMM3 partials: P[ks][4096][48] = xcb @ Wxt^T ------------
__global__ __launch_bounds__(256) void gemm3_mfma(
    const ushort* __restrict__ A, const ushort* __restrict__ Bt,
    float* __restrict__ P)
{
    __shared__ ushort lA[64 * 64];
    __shared__ ushort lB[48 * 64];
    const int t = threadIdx.x;
    const int w = t >> 6, ln = t & 63;
    const int q = ln >> 4, r = ln & 15;
    const int bm = blockIdx.y * 64;
    const int ks = blockIdx.x;
    f32x4 acc[3] = {};

    for (int k0 = ks * 256; k0 < ks * 256 + 256; k0 += 64) {
        #pragma unroll
        for (int j = 0; j < 2; ++j) {
            int i = (w * 2 + j) * 64 + ln;
            int m = i >> 3, k8 = (i & 7) * 8;
            __builtin_amdgcn_global_load_lds(
                (const __attribute__((address_space(1))) void*)(A + (size_t)(bm + m) * 1024 + k0 + k8),
                (__attribute__((address_space(3))) void*)(lA + (size_t)i * 8),
                16, 0, 0);
        }
        #pragma unroll
        for (int p = 0; p < 2; ++p) {
            int cidx = p * 4 + w;
            if (cidx < 6) {
                int i = cidx * 64 + ln;
                int m = i >> 3, k8 = (i & 7) * 8;
                __builtin_amdgcn_global_load_lds(
                    (const __attribute__((address_space(1))) void*)(Bt + (size_t)m * 1024 + k0 + k8),
                    (__attribute__((address_space(3))) void*)(lB + (size_t)i * 8),
                    16, 0, 0);
            }
        }
        __syncthreads();
        #pragma unroll
        for (int kk = 0; kk < 2; ++kk) {
            const int ko = kk * 32 + q * 8;
            bf16x8 af = *reinterpret_cast<const bf16x8*>(&lA[(w * 16 + r) * 64 + ko]);
            #pragma unroll
            for (int n = 0; n < 3; ++n) {
                bf16x8 bf = *reinterpret_cast<const bf16x8*>(&lB[(n * 16 + r) * 64 + ko]);
                acc[n] = __builtin_amdgcn_mfma_f32_16x16x32_bf16(af, bf, acc[n], 0, 0, 0);
            }
        }
        __syncthreads();
    }

    const int row0 = bm + w * 16 + q * 4;
    const size_t base = (size_t)ks * 196608;
    #pragma unroll
    for (int n = 0; n < 3; ++n)
        #pragma unroll
        for (int j = 0; j < 4; ++j)
            P[base + (size_t)(row0 + j) * 48 + n * 16 + r] = acc[n][j];
}

// ---------------- prep: all input casts in one launch ----------------------
__global__ __launch_bounds__(256) void prep_all(
    const float* __restrict__ x, const float* __restrict__ W_in,
    const float* __restrict__ W_out, const float* __restrict__ W_x,
    ushort* __restrict__ xbf, ushort* __restrict__ Wt1,
    ushort* __restrict__ Wt2, ushort* __restrict__ Wxt)
{
    const int bid = blockIdx.x;
    const int t = threadIdx.x;
    if (bid < 2048) {
        int i = bid * 256 + t;
        float4 v = reinterpret_cast<const float4*>(x)[i];
        ushort4 o;
        o.x = bf16_bits(v.x); o.y = bf16_bits(v.y);
        o.z = bf16_bits(v.z); o.w = bf16_bits(v.w);
        reinterpret_cast<ushort4*>(xbf)[i] = o;
        return;
    }
    if (bid >= 2432) {
        int idx = (bid - 2432) * 256 + t;            // < 49152
        int c = idx >> 10, k = idx & 1023;
        Wxt[idx] = (c < 33) ? bf16_bits(W_x[(size_t)k * 33 + c]) : (ushort)0;
        return;
    }
    __shared__ float ld[64][65];
    const float* src; ushort* dst; int R, C, tile;
    if (bid < 2304) { src = W_in;  dst = Wt1; R = 512;  C = 2048; tile = bid - 2048; }
    else            { src = W_out; dst = Wt2; R = 1024; C = 512;  tile = bid - 2304; }
    const int ctiles = C / 64;
    const int r0 = (tile / ctiles) * 64, c0 = (tile % ctiles) * 64;
    #pragma unroll
    for (int i = 0; i < 16; ++i) {
        int idx = t + i * 256;
        int rr = idx >> 6, cc = idx & 63;
        ld[rr][cc] = src[(size_t)(r0 + rr) * C + c0 + cc];
    }
    __syncthreads();
    #pragma unroll
    for (int i = 0; i < 16; ++i) {
        int idx = t + i * 256;
        int cc = idx >> 6, rr = idx & 63;
        dst[(size_t)(c0 + cc) * R + r0 + rr] = bf16_bits(ld[rr][cc]);
    }
}

// ---------------- depthwise causal conv(4) + SiLU (bf16 in/out) ------------
__global__ __launch_bounds__(256) void conv_silu(
    const ushort* __restrict__ xinb, const float* __restrict__ cw,
    const float* __restrict__ cb, ushort* __restrict__ xcb)
{
    int idx = blockIdx.x * 256 + threadIdx.x;
    int d = idx & (DI - 1);
    int l = (idx >> 10) & (L_SEQ - 1);
    float4 w = *reinterpret_cast<const float4*>(cw + d * 4);
    float acc = cb[d];
    long base = (long)idx;
    if (l >= 3) acc = fmaf(bf2f(xinb[base - 3 * 1024]), w.x, acc);
    if (l >= 2) acc = fmaf(bf2f(xinb[base - 2 * 1024]), w.y, acc);
    if (l >= 1) acc = fmaf(bf2f(xinb[base - 1 * 1024]), w.z, acc);
    acc = fmaf(bf2f(xinb[base]), w.w, acc);
    xcb[idx] = bf16_bits(silu_f(acc));
}

// ---------------- rates + GEMM3 reduce, one launch --------------------------
// blocks 0..1   : per-batch log-space rate scan (reads raw dt from P directly)
// blocks 2..513 : scal[l][c] = b_x[c] + sum_ks P[ks][l][c]   (c < 32)
__global__ __launch_bounds__(256) void rates_fused(
    const float* __restrict__ P, const float* __restrict__ b_x,
    float* __restrict__ scal, const float* __restrict__ A_log,
    float* __restrict__ RP)
{
    const int bid = blockIdx.x;
    const int t = threadIdx.x;

    if (bid >= 2) {
        int idx = (bid - 2) * 256 + t;               // < 131072
        int l = idx >> 5, c = idx & 31;
        int pi = l * 48 + c;
        float v = b_x[c] + P[pi] + P[pi + 196608] + P[pi + 393216] + P[pi + 589824];
        scal[(size_t)l * 48 + c] = v;
        return;
    }

    const int b = bid;
    __shared__ float cdt[L_SEQ];
    __shared__ float wsum[4];
    __shared__ float An[16];
    if (t < 16) An[t] = -__expf(A_log[t]);
    float* base = scal + (long)b * L_SEQ * 48;
    const float bdt = b_x[32];

    float dt[8];
    float run = 0.f;
    const int l0 = t * 8;
    #pragma unroll
    for (int i = 0; i < 8; ++i) {
        int gl = b * L_SEQ + l0 + i;                 // global row for P
        int pi = gl * 48 + 32;
        float raw = bdt + P[pi] + P[pi + 196608] + P[pi + 393216] + P[pi + 589824];
        float d = (raw > 20.f) ? raw : log1pf(__expf(raw));
        dt[i] = d;
        run += d;
        cdt[l0 + i] = run;
    }

    float x = run;
    int lane = t & 63;
    #pragma unroll
    for (int d = 1; d < 64; d <<= 1) {
        float v = __shfl_up(x, d, 64);
        if (lane >= d) x += v;
    }
    int w = t >> 6;
    if (lane == 63) wsum[w] = x;
    __syncthreads();
    float woff = 0.f;
    for (int i = 0; i < w; ++i) woff += wsum[i];
    float toff = woff + x - run;
    #pragma unroll
    for (int i = 0; i < 8; ++i) cdt[l0 + i] += toff;
    __syncthreads();

    float cprev = (l0 == 0) ? 0.f : cdt[l0 - 1];
    #pragma unroll
    for (int i = 0; i < 8; ++i) {
        int l = l0 + i;
        float cl = cdt[l];
        float rv[16];
        #pragma unroll
        for (int s = 0; s < 16; ++s) {
            float A = An[s];
            float rr;
            if (A * cl >= LOG_EPS) {
                rr = __expf(A * dt[i]);
            } else {
                float lp = A * cprev;
                rr = (lp >= LOG_EPS) ? EPS_F / __expf(lp) : 1.f;
            }
            rv[s] = rr;
        }
        float4* dst = reinterpret_cast<float4*>(base + l * 48 + 32);
        dst[0] = *reinterpret_cast<float4*>(&rv[0]);
        dst[1] = *reinterpret_cast<float4*>(&rv[4]);
        dst[2] = *reinterpret_cast<float4*>(&rv[8]);
        dst[3] = *reinterpret_cast<float4*>(&rv[12]);
        cprev = cl;
    }

    if ((t & 3) == 3) {
        int c = t >> 2;
        float ce = cdt[c * LC + LC - 1];
        float cp = (c == 0) ? 0.f : cdt[c * LC - 1];
        for (int s = 0; s < 16; ++s) {
            float A = An[s];
            float pe = fmaxf(__expf(A * ce), EPS_F);
            float pp = fmaxf(__expf(A * cp), EPS_F);
            RP[(b * NC + c) * 16 + s] = pe / pp;
        }
    }
}

// ---------------- cooperative fused scan: states + stitch + out ------------
// Grid 1024 x 128. Block bx: dblk = bx&7, chunk c = (bx>>3)&63, batch b = bx>>9.
// xv (chunk inputs) held in registers and sc (scal slice) in LDS across the
// two grid syncs — phase B re-reads nothing but Sbf/resb.
__global__ __launch_bounds__(128, 2) void scan3(
    const float* __restrict__ scal, const ushort* __restrict__ xcb,
    const ushort* __restrict__ resb, const float* __restrict__ RP,
    const float* __restrict__ Dw, ushort* Sbf, ushort* __restrict__ ybf)
{
    cg::grid_group grid = cg::this_grid();
    const int bx = blockIdx.x;
    const int dblk = bx & 7, c = (bx >> 3) & (NC - 1), b = bx >> 9;
    const int d = dblk * 128 + threadIdx.x;

    __shared__ float sc[LC * 48];
    const float4* src = reinterpret_cast<const float4*>(scal + ((long)(b * L_SEQ) + c * LC) * 48);
    float4* dst4 = reinterpret_cast<float4*>(sc);
    for (int i = threadIdx.x; i < LC * 48 / 4; i += 128) dst4[i] = src[i];

    const long row0 = (long)(b * L_SEQ) + c * LC;
    float xv[LC];
    #pragma unroll
    for (int ll = 0; ll < LC; ++ll) xv[ll] = bf2f(xcb[(row0 + ll) * 1024 + d]);
    __syncthreads();

    // ---- phase A: local chunk end states -> Sbf
    {
        float h[16];
        #pragma unroll
        for (int s = 0; s < 16; ++s) h[s] = 0.f;
        #pragma unroll
        for (int ll = 0; ll < LC; ++ll) {
            const float* e = sc + ll * 48;
            #pragma unroll
            for (int s = 0; s < 16; ++s) h[s] = fmaf(e[32 + s], h[s], e[s] * xv[ll]);
        }
        ushort* Sp = Sbf + ((long)(b * NC + c) * 16) * 1024 + d;
        #pragma unroll
        for (int s = 0; s < 16; ++s) Sp[(long)s * 1024] = bf16_bits(h[s]);
    }

    grid.sync();

    // ---- stitch: blocks 0..255 (32768 threads = one per (b,s,d))
    if (bx < 256) {
        int idx = bx * 128 + (int)threadIdx.x;
        int b2 = idx >> 14;
        int s2 = (idx >> 10) & 15;
        int d2 = idx & 1023;
        const long sbase = ((long)(b2 * NC) * 16 + s2) * 1024 + d2;
        const long cs = 16 * 1024;
        float H = 0.f;
        #pragma unroll
        for (int g = 0; g < NC / 8; ++g) {
            float v[8];
            #pragma unroll
            for (int k = 0; k < 8; ++k) v[k] = bf2f(Sbf[sbase + (long)(g * 8 + k) * cs]);
            #pragma unroll
            for (int k = 0; k < 8; ++k) {
                int c2 = g * 8 + k;
                float tmp = v[k];
                Sbf[sbase + (long)c2 * cs] = bf16_bits(H);
                H = fmaf(RP[(b2 * NC + c2) * 16 + s2], H, tmp);
            }
        }
    }

    grid.sync();

    // ---- phase B: corrected init state, full scan + y + gate -> ybf
    float rv[LC];
    #pragma unroll
    for (int ll = 0; ll < LC; ++ll) rv[ll] = bf2f(resb[(row0 + ll) * 1024 + d]);
    float h[16];
    {
        const ushort* Hp = Sbf + ((long)(b * NC + c) * 16) * 1024 + d;
        #pragma unroll
        for (int s = 0; s < 16; ++s) h[s] = bf2f(Hp[(long)s * 1024]);
    }
    const float Dd = Dw[d];
    #pragma unroll
    for (int ll = 0; ll < LC; ++ll) {
        const float* e = sc + ll * 48;
        float y = 0.f;
        #pragma unroll
        for (int s = 0; s < 16; ++s) {
            h[s] = fmaf(e[32 + s], h[s], e[s] * xv[ll]);
            y = fmaf(e[16 + s], h[s], y);
        }
        y = fmaf(Dd, xv[ll], y);
        ybf[(row0 + ll) * 1024 + d] = bf16_bits(y * silu_f(rv[ll]));
    }
}

// ---------------------------------------------------------------------------
extern "C" void kernel_launch(void* const* d_in, const int* in_sizes, int n_in,
                              void* d_out, int out_size, void* d_ws, size_t ws_size,
                              hipStream_t stream)
{
    const float* x      = (const float*)d_in[0];
    const float* W_in   = (const float*)d_in[1];
    const float* b_in   = (const float*)d_in[2];
    const float* conv_w = (const float*)d_in[3];
    const float* conv_b = (const float*)d_in[4];
    const float* W_x    = (const float*)d_in[5];
    const float* b_x    = (const float*)d_in[6];
    const float* A_log  = (const float*)d_in[7];
    const float* Dw     = (const float*)d_in[8];
    const float* W_out  = (const float*)d_in[9];
    const float* b_out  = (const float*)d_in[10];
    float* out = (float*)d_out;

    ushort* u    = (ushort*)d_ws;
    ushort* xinb = u;                           // 4,194,304 u
    ushort* resb = xinb + 4194304;              // 4,194,304 u
    ushort* xcb  = resb + 4194304;              // 4,194,304 u
    ushort* Sbf  = xcb + 4194304;               // 2,097,152 u
    ushort* xbf  = Sbf + 2097152;               // 2,097,152 u
    ushort* Wt1  = xbf + 2097152;               // 1,048,576 u
    ushort* Wt2  = Wt1 + 1048576;               //   524,288 u
    ushort* Wxt  = Wt2 + 524288;                //    49,152 u
    ushort* ybf  = Wxt + 49152;                 // 4,194,304 u
    float* scal  = (float*)(ybf + 4194304);     //   196,608 f
    float* RP    = scal + 196608;               //     2,048 f
    float* P     = RP + 2048;                   //   786,432 f

    // 0. all input casts
    prep_all<<<2624, 256, 0, stream>>>(x, W_in, W_out, W_x, xbf, Wt1, Wt2, Wxt);

    // 1. [xinb | resb] = x @ W_in + b_in
    gemm1_mfma<<<dim3(2048 / 128, 4096 / 128), 256, 0, stream>>>(
        xbf, Wt1, b_in, xinb, resb, 4096, 2048, 512);

    // 2. xcb = bf16(silu(conv(xinb)))
    conv_silu<<<(NBATCH * L_SEQ * DI) / 256, 256, 0, stream>>>(xinb, conv_w, conv_b, xcb);

    // 3. GEMM3 partials (B, C, dt)
    gemm3_mfma<<<dim3(4, 4096 / 64), 256, 0, stream>>>(xcb, Wxt, P);

    // 4. rates (blocks 0-1) + B/C reduce (blocks 2-513), one launch
    rates_fused<<<514, 256, 0, stream>>>(P, b_x, scal, A_log, RP);

    // 5. cooperative fused scan (states + stitch + out)
    {
        void* args[] = {(void*)&scal, (void*)&xcb, (void*)&resb, (void*)&RP,
                        (void*)&Dw, (void*)&Sbf, (void*)&ybf};
        hipLaunchCooperativeKernel((void*)scan3, dim3(1024), dim3(128),
                                   args, 0, stream);
    }

    // 6. out = y_act @ W_out + b_out
    gemm2_mfma<<<dim3(512 / 64, 4096 / 128), 256, 0, stream>>>(
        ybf, Wt2, b_out, out, 4096, 512, 1024);
}

// Round 10
// 120.824 us; speedup vs baseline: 3.1075x; 3.1075x over previous
//
#include <hip/hip_runtime.h>
#include <hip/hip_bf16.h>
#include <cmath>

// ---------------------------------------------------------------------------
// Mamba block, round 10: round-8 structure + rates_fused (9 launches).
//   prep_all -> gemm1 -> conv_silu -> gemm3 -> rates_fused(+reduce)
//   -> scan_states -> stitch -> scan_out -> gemm2
//   B=2, L=2048, D_MODEL=512, D_INNER=1024, D_STATE=16, D_CONV=4, EPS=1e-8
// NOTE (r9 lesson): grid.sync() on MI355X costs ~100µs+ per sync at this
// footprint (cross-XCD coherence flush); kernel boundaries are the cheap
// grid barrier. Do not re-fuse the scan chain cooperatively.
// ---------------------------------------------------------------------------

#define L_SEQ 2048
#define NBATCH 2
#define DI 1024
#define NC 64
#define LC 32
#define EPS_F 1e-8f
#define LOG_EPS -18.420680744f

typedef __attribute__((ext_vector_type(8))) __bf16 bf16x8;
typedef __attribute__((ext_vector_type(4))) float f32x4;

__device__ __forceinline__ float silu_f(float v) {
    return v / (1.f + __expf(-v));
}

__device__ __forceinline__ ushort bf16_bits(float v) {
    __hip_bfloat16 h = __float2bfloat16(v);
    return *reinterpret_cast<ushort*>(&h);
}

__device__ __forceinline__ float bf2f(ushort u) {
    union { unsigned u; float f; } c;
    c.u = ((unsigned)u) << 16;
    return c.f;
}

// ---------------- GEMM1: [xinb | resb] = x @ W_in^T + b (bf16 out) ---------
__global__ __launch_bounds__(256) void gemm1_mfma(
    const ushort* __restrict__ A, const ushort* __restrict__ Bt,
    const float* __restrict__ bias, ushort* __restrict__ C0,
    ushort* __restrict__ C1, int M, int N, int K)
{
    __shared__ ushort lA[128 * 64];
    __shared__ ushort lB[128 * 64];
    const int tid = threadIdx.x;
    const int w = tid >> 6, ln = tid & 63;
    const int wr = w >> 1, wc = w & 1;
    const int bm = blockIdx.y * 128, bn = blockIdx.x * 128;
    const int q = ln >> 4, r = ln & 15;
    f32x4 acc[4][4] = {};

    for (int k0 = 0; k0 < K; k0 += 64) {
        #pragma unroll
        for (int j = 0; j < 4; ++j) {
            int i = (w * 4 + j) * 64 + ln;
            int m = i >> 3, k8 = (i & 7) * 8;
            __builtin_amdgcn_global_load_lds(
                (const __attribute__((address_space(1))) void*)(A + (size_t)(bm + m) * K + k0 + k8),
                (__attribute__((address_space(3))) void*)(lA + (size_t)i * 8),
                16, 0, 0);
            __builtin_amdgcn_global_load_lds(
                (const __attribute__((address_space(1))) void*)(Bt + (size_t)(bn + m) * K + k0 + k8),
                (__attribute__((address_space(3))) void*)(lB + (size_t)i * 8),
                16, 0, 0);
        }
        __syncthreads();
        #pragma unroll
        for (int kk = 0; kk < 2; ++kk) {
            const int ko = kk * 32 + q * 8;
            bf16x8 af[4], bfr[4];
            #pragma unroll
            for (int m = 0; m < 4; ++m)
                af[m] = *reinterpret_cast<const bf16x8*>(&lA[(wr * 64 + m * 16 + r) * 64 + ko]);
            #pragma unroll
            for (int n = 0; n < 4; ++n)
                bfr[n] = *reinterpret_cast<const bf16x8*>(&lB[(wc * 64 + n * 16 + r) * 64 + ko]);
            #pragma unroll
            for (int m = 0; m < 4; ++m)
                #pragma unroll
                for (int n = 0; n < 4; ++n)
                    acc[m][n] = __builtin_amdgcn_mfma_f32_16x16x32_bf16(af[m], bfr[n], acc[m][n], 0, 0, 0);
        }
        __syncthreads();
    }

    const bool lo = (bn < 1024);
    #pragma unroll
    for (int n = 0; n < 4; ++n) {
        int col = bn + wc * 64 + n * 16 + r;
        float bv = bias[col];
        #pragma unroll
        for (int m = 0; m < 4; ++m) {
            int row0 = bm + wr * 64 + m * 16 + q * 4;
            #pragma unroll
            for (int j = 0; j < 4; ++j) {
                ushort v = bf16_bits(acc[m][n][j] + bv);
                if (lo) C0[(size_t)(row0 + j) * 1024 + col] = v;
                else    C1[(size_t)(row0 + j) * 1024 + (col - 1024)] = v;
            }
        }
    }
}

// ---------------- GEMM2: out = ybf @ Wt2^T + b (f32 out, 128x64 tile) ------
__global__ __launch_bounds__(256) void gemm2_mfma(
    const ushort* __restrict__ A, const ushort* __restrict__ Bt,
    const float* __restrict__ bias, float* __restrict__ C,
    int M, int N, int K)
{
    __shared__ ushort lA[128 * 64];
    __shared__ ushort lB[64 * 64];
    const int tid = threadIdx.x;
    const int w = tid >> 6, ln = tid & 63;
    const int wr = w >> 1, wc = w & 1;
    const int bm = blockIdx.y * 128, bn = blockIdx.x * 64;
    const int q = ln >> 4, r = ln & 15;
    f32x4 acc[4][2] = {};

    for (int k0 = 0; k0 < K; k0 += 64) {
        #pragma unroll
        for (int j = 0; j < 4; ++j) {
            int i = (w * 4 + j) * 64 + ln;
            int m = i >> 3, k8 = (i & 7) * 8;
            __builtin_amdgcn_global_load_lds(
                (const __attribute__((address_space(1))) void*)(A + (size_t)(bm + m) * K + k0 + k8),
                (__attribute__((address_space(3))) void*)(lA + (size_t)i * 8),
                16, 0, 0);
        }
        #pragma unroll
        for (int j = 0; j < 2; ++j) {
            int i = (w * 2 + j) * 64 + ln;
            int m = i >> 3, k8 = (i & 7) * 8;
            __builtin_amdgcn_global_load_lds(
                (const __attribute__((address_space(1))) void*)(Bt + (size_t)(bn + m) * K + k0 + k8),
                (__attribute__((address_space(3))) void*)(lB + (size_t)i * 8),
                16, 0, 0);
        }
        __syncthreads();
        #pragma unroll
        for (int kk = 0; kk < 2; ++kk) {
            const int ko = kk * 32 + q * 8;
            bf16x8 af[4], bfr[2];
            #pragma unroll
            for (int m = 0; m < 4; ++m)
                af[m] = *reinterpret_cast<const bf16x8*>(&lA[(wr * 64 + m * 16 + r) * 64 + ko]);
            #pragma unroll
            for (int n = 0; n < 2; ++n)
                bfr[n] = *reinterpret_cast<const bf16x8*>(&lB[(wc * 32 + n * 16 + r) * 64 + ko]);
            #pragma unroll
            for (int m = 0; m < 4; ++m)
                #pragma unroll
                for (int n = 0; n < 2; ++n)
                    acc[m][n] = __builtin_amdgcn_mfma_f32_16x16x32_bf16(af[m], bfr[n], acc[m][n], 0, 0, 0);
        }
        __syncthreads();
    }

    #pragma unroll
    for (int n = 0; n < 2; ++n) {
        int col = bn + wc * 32 + n * 16 + r;
        float bv = bias[col];
        #pragma unroll
        for (int m = 0; m < 4; ++m) {
            int row0 = bm + wr * 64 + m * 16 + q * 4;
            #pragma unroll
            for (int j = 0; j < 4; ++j)
                C[(size_t)(row0 + j) * N + col] = acc[m][n][j] + bv;
        }
    }
}

// ---------------- GEMM3 partials: P[ks][4096][48] = xcb @ Wxt^T ------------
__global__ __launch_bounds__(256) void gemm3_mfma(
    const ushort* __restrict__ A, const ushort* __restrict__ Bt,
    float* __restrict__ P)
{
    __shared__ ushort lA[64 * 64];
    __shared__ ushort lB[48 * 64];
    const int t = threadIdx.x;
    const int w = t >> 6, ln = t & 63;
    const int q = ln >> 4, r = ln & 15;
    const int bm = blockIdx.y * 64;
    const int ks = blockIdx.x;
    f32x4 acc[3] = {};

    for (int k0 = ks * 256; k0 < ks * 256 + 256; k0 += 64) {
        #pragma unroll
        for (int j = 0; j < 2; ++j) {
            int i = (w * 2 + j) * 64 + ln;
            int m = i >> 3, k8 = (i & 7) * 8;
            __builtin_amdgcn_global_load_lds(
                (const __attribute__((address_space(1))) void*)(A + (size_t)(bm + m) * 1024 + k0 + k8),
                (__attribute__((address_space(3))) void*)(lA + (size_t)i * 8),
                16, 0, 0);
        }
        #pragma unroll
        for (int p = 0; p < 2; ++p) {
            int cidx = p * 4 + w;
            if (cidx < 6) {
                int i = cidx * 64 + ln;
                int m = i >> 3, k8 = (i & 7) * 8;
                __builtin_amdgcn_global_load_lds(
                    (const __attribute__((address_space(1))) void*)(Bt + (size_t)m * 1024 + k0 + k8),
                    (__attribute__((address_space(3))) void*)(lB + (size_t)i * 8),
                    16, 0, 0);
            }
        }
        __syncthreads();
        #pragma unroll
        for (int kk = 0; kk < 2; ++kk) {
            const int ko = kk * 32 + q * 8;
            bf16x8 af = *reinterpret_cast<const bf16x8*>(&lA[(w * 16 + r) * 64 + ko]);
            #pragma unroll
            for (int n = 0; n < 3; ++n) {
                bf16x8 bf = *reinterpret_cast<const bf16x8*>(&lB[(n * 16 + r) * 64 + ko]);
                acc[n] = __builtin_amdgcn_mfma_f32_16x16x32_bf16(af, bf, acc[n], 0, 0, 0);
            }
        }
        __syncthreads();
    }

    const int row0 = bm + w * 16 + q * 4;
    const size_t base = (size_t)ks * 196608;
    #pragma unroll
    for (int n = 0; n < 3; ++n)
        #pragma unroll
        for (int j = 0; j < 4; ++j)
            P[base + (size_t)(row0 + j) * 48 + n * 16 + r] = acc[n][j];
}

// ---------------- prep: all input casts in one launch ----------------------
__global__ __launch_bounds__(256) void prep_all(
    const float* __restrict__ x, const float* __restrict__ W_in,
    const float* __restrict__ W_out, const float* __restrict__ W_x,
    ushort* __restrict__ xbf, ushort* __restrict__ Wt1,
    ushort* __restrict__ Wt2, ushort* __restrict__ Wxt)
{
    const int bid = blockIdx.x;
    const int t = threadIdx.x;
    if (bid < 2048) {
        int i = bid * 256 + t;
        float4 v = reinterpret_cast<const float4*>(x)[i];
        ushort4 o;
        o.x = bf16_bits(v.x); o.y = bf16_bits(v.y);
        o.z = bf16_bits(v.z); o.w = bf16_bits(v.w);
        reinterpret_cast<ushort4*>(xbf)[i] = o;
        return;
    }
    if (bid >= 2432) {
        int idx = (bid - 2432) * 256 + t;            // < 49152
        int c = idx >> 10, k = idx & 1023;
        Wxt[idx] = (c < 33) ? bf16_bits(W_x[(size_t)k * 33 + c]) : (ushort)0;
        return;
    }
    __shared__ float ld[64][65];
    const float* src; ushort* dst; int R, C, tile;
    if (bid < 2304) { src = W_in;  dst = Wt1; R = 512;  C = 2048; tile = bid - 2048; }
    else            { src = W_out; dst = Wt2; R = 1024; C = 512;  tile = bid - 2304; }
    const int ctiles = C / 64;
    const int r0 = (tile / ctiles) * 64, c0 = (tile % ctiles) * 64;
    #pragma unroll
    for (int i = 0; i < 16; ++i) {
        int idx = t + i * 256;
        int rr = idx >> 6, cc = idx & 63;
        ld[rr][cc] = src[(size_t)(r0 + rr) * C + c0 + cc];
    }
    __syncthreads();
    #pragma unroll
    for (int i = 0; i < 16; ++i) {
        int idx = t + i * 256;
        int cc = idx >> 6, rr = idx & 63;
        dst[(size_t)(c0 + cc) * R + r0 + rr] = bf16_bits(ld[rr][cc]);
    }
}

// ---------------- depthwise causal conv(4) + SiLU (bf16 in/out) ------------
__global__ __launch_bounds__(256) void conv_silu(
    const ushort* __restrict__ xinb, const float* __restrict__ cw,
    const float* __restrict__ cb, ushort* __restrict__ xcb)
{
    int idx = blockIdx.x * 256 + threadIdx.x;
    int d = idx & (DI - 1);
    int l = (idx >> 10) & (L_SEQ - 1);
    float4 w = *reinterpret_cast<const float4*>(cw + d * 4);
    float acc = cb[d];
    long base = (long)idx;
    if (l >= 3) acc = fmaf(bf2f(xinb[base - 3 * 1024]), w.x, acc);
    if (l >= 2) acc = fmaf(bf2f(xinb[base - 2 * 1024]), w.y, acc);
    if (l >= 1) acc = fmaf(bf2f(xinb[base - 1 * 1024]), w.z, acc);
    acc = fmaf(bf2f(xinb[base]), w.w, acc);
    xcb[idx] = bf16_bits(silu_f(acc));
}

// ---------------- rates + GEMM3 reduce, one launch --------------------------
// blocks 0..1   : per-batch log-space rate scan (reads raw dt from P directly)
// blocks 2..513 : scal[l][c] = b_x[c] + sum_ks P[ks][l][c]   (c < 32)
__global__ __launch_bounds__(256) void rates_fused(
    const float* __restrict__ P, const float* __restrict__ b_x,
    float* __restrict__ scal, const float* __restrict__ A_log,
    float* __restrict__ RP)
{
    const int bid = blockIdx.x;
    const int t = threadIdx.x;

    if (bid >= 2) {
        int idx = (bid - 2) * 256 + t;               // < 131072
        int l = idx >> 5, c = idx & 31;
        int pi = l * 48 + c;
        float v = b_x[c] + P[pi] + P[pi + 196608] + P[pi + 393216] + P[pi + 589824];
        scal[(size_t)l * 48 + c] = v;
        return;
    }

    const int b = bid;
    __shared__ float cdt[L_SEQ];
    __shared__ float wsum[4];
    __shared__ float An[16];
    if (t < 16) An[t] = -__expf(A_log[t]);
    float* base = scal + (long)b * L_SEQ * 48;
    const float bdt = b_x[32];

    float dt[8];
    float run = 0.f;
    const int l0 = t * 8;
    #pragma unroll
    for (int i = 0; i < 8; ++i) {
        int gl = b * L_SEQ + l0 + i;
        int pi = gl * 48 + 32;
        float raw = bdt + P[pi] + P[pi + 196608] + P[pi + 393216] + P[pi + 589824];
        float d = (raw > 20.f) ? raw : log1pf(__expf(raw));
        dt[i] = d;
        run += d;
        cdt[l0 + i] = run;
    }

    float x = run;
    int lane = t & 63;
    #pragma unroll
    for (int d = 1; d < 64; d <<= 1) {
        float v = __shfl_up(x, d, 64);
        if (lane >= d) x += v;
    }
    int w = t >> 6;
    if (lane == 63) wsum[w] = x;
    __syncthreads();
    float woff = 0.f;
    for (int i = 0; i < w; ++i) woff += wsum[i];
    float toff = woff + x - run;
    #pragma unroll
    for (int i = 0; i < 8; ++i) cdt[l0 + i] += toff;
    __syncthreads();

    float cprev = (l0 == 0) ? 0.f : cdt[l0 - 1];
    #pragma unroll
    for (int i = 0; i < 8; ++i) {
        int l = l0 + i;
        float cl = cdt[l];
        float rv[16];
        #pragma unroll
        for (int s = 0; s < 16; ++s) {
            float A = An[s];
            float rr;
            if (A * cl >= LOG_EPS) {
                rr = __expf(A * dt[i]);
            } else {
                float lp = A * cprev;
                rr = (lp >= LOG_EPS) ? EPS_F / __expf(lp) : 1.f;
            }
            rv[s] = rr;
        }
        float4* dst = reinterpret_cast<float4*>(base + l * 48 + 32);
        dst[0] = *reinterpret_cast<float4*>(&rv[0]);
        dst[1] = *reinterpret_cast<float4*>(&rv[4]);
        dst[2] = *reinterpret_cast<float4*>(&rv[8]);
        dst[3] = *reinterpret_cast<float4*>(&rv[12]);
        cprev = cl;
    }

    if ((t & 3) == 3) {
        int c = t >> 2;
        float ce = cdt[c * LC + LC - 1];
        float cp = (c == 0) ? 0.f : cdt[c * LC - 1];
        for (int s = 0; s < 16; ++s) {
            float A = An[s];
            float pe = fmaxf(__expf(A * ce), EPS_F);
            float pp = fmaxf(__expf(A * cp), EPS_F);
            RP[(b * NC + c) * 16 + s] = pe / pp;
        }
    }
}

// ---------------- phase A: per-chunk local end states (bf16 in/out) --------
__global__ __launch_bounds__(128) void scan_states(
    const float* __restrict__ scal, const ushort* __restrict__ xcb,
    ushort* __restrict__ Sbf)
{
    int b = blockIdx.z, c = blockIdx.y;
    int d = blockIdx.x * 128 + threadIdx.x;
    __shared__ float sc[LC * 48];
    const float4* src = reinterpret_cast<const float4*>(scal + ((long)(b * L_SEQ) + c * LC) * 48);
    float4* dst = reinterpret_cast<float4*>(sc);
    for (int i = threadIdx.x; i < LC * 48 / 4; i += 128) dst[i] = src[i];

    const ushort* xcp = xcb + ((long)(b * L_SEQ) + c * LC) * 1024 + d;
    float xv[LC];
    #pragma unroll
    for (int ll = 0; ll < LC; ++ll) xv[ll] = bf2f(xcp[(long)ll * 1024]);
    __syncthreads();

    float h[16];
    #pragma unroll
    for (int s = 0; s < 16; ++s) h[s] = 0.f;
    #pragma unroll
    for (int ll = 0; ll < LC; ++ll) {
        const float* e = sc + ll * 48;
        #pragma unroll
        for (int s = 0; s < 16; ++s) h[s] = fmaf(e[32 + s], h[s], e[s] * xv[ll]);
    }
    ushort* Sp = Sbf + ((long)(b * NC + c) * 16) * 1024 + d;
    #pragma unroll
    for (int s = 0; s < 16; ++s) Sp[(long)s * 1024] = bf16_bits(h[s]);
}

// ---------------- stitch (in-place, batched) --------------------------------
__global__ __launch_bounds__(256) void stitch(
    ushort* __restrict__ Sbf, const float* __restrict__ RP)
{
    const int tid = threadIdx.x;
    const int idx = blockIdx.x * 256 + tid;
    const int b = blockIdx.y;
    const int d = idx & 1023, s = idx >> 10;
    __shared__ float rps[NC];
    if (tid < NC) rps[tid] = RP[(b * NC + tid) * 16 + s];

    const long base = ((long)(b * NC) * 16 + s) * 1024 + d;
    const long cs = 16 * 1024;
    float v[NC];
    #pragma unroll
    for (int c = 0; c < NC; ++c) v[c] = bf2f(Sbf[base + c * cs]);
    __syncthreads();
    float H = 0.f;
    #pragma unroll
    for (int c = 0; c < NC; ++c) {
        float tmp = v[c];
        v[c] = H;
        H = fmaf(rps[c], H, tmp);
    }
    #pragma unroll
    for (int c = 0; c < NC; ++c) Sbf[base + c * cs] = bf16_bits(v[c]);
}

// ---------------- phase B: full scan + y + gating -> bf16 ------------------
__global__ __launch_bounds__(128) void scan_out(
    const float* __restrict__ scal, const ushort* __restrict__ xcb,
    const ushort* __restrict__ Hin, const float* __restrict__ Dw,
    const ushort* __restrict__ resb, ushort* __restrict__ ybf)
{
    int b = blockIdx.z, c = blockIdx.y;
    int d = blockIdx.x * 128 + threadIdx.x;
    __shared__ float sc[LC * 48];
    const float4* src = reinterpret_cast<const float4*>(scal + ((long)(b * L_SEQ) + c * LC) * 48);
    float4* dst = reinterpret_cast<float4*>(sc);
    for (int i = threadIdx.x; i < LC * 48 / 4; i += 128) dst[i] = src[i];

    const long row0 = (long)(b * L_SEQ) + c * LC;
    float xv[LC], rv[LC];
    #pragma unroll
    for (int ll = 0; ll < LC; ++ll) xv[ll] = bf2f(xcb[(row0 + ll) * 1024 + d]);
    #pragma unroll
    for (int ll = 0; ll < LC; ++ll) rv[ll] = bf2f(resb[(row0 + ll) * 1024 + d]);
    float h[16];
    long hoff = ((long)(b * NC + c) * 16) * 1024 + d;
    #pragma unroll
    for (int s = 0; s < 16; ++s) h[s] = bf2f(Hin[hoff + (long)s * 1024]);
    __syncthreads();

    float Dd = Dw[d];
    #pragma unroll
    for (int ll = 0; ll < LC; ++ll) {
        const float* e = sc + ll * 48;
        float y = 0.f;
        #pragma unroll
        for (int s = 0; s < 16; ++s) {
            h[s] = fmaf(e[32 + s], h[s], e[s] * xv[ll]);
            y = fmaf(e[16 + s], h[s], y);
        }
        y = fmaf(Dd, xv[ll], y);
        ybf[(row0 + ll) * 1024 + d] = bf16_bits(y * silu_f(rv[ll]));
    }
}

// ---------------------------------------------------------------------------
extern "C" void kernel_launch(void* const* d_in, const int* in_sizes, int n_in,
                              void* d_out, int out_size, void* d_ws, size_t ws_size,
                              hipStream_t stream)
{
    const float* x      = (const float*)d_in[0];
    const float* W_in   = (const float*)d_in[1];
    const float* b_in   = (const float*)d_in[2];
    const float* conv_w = (const float*)d_in[3];
    const float* conv_b = (const float*)d_in[4];
    const float* W_x    = (const float*)d_in[5];
    const float* b_x    = (const float*)d_in[6];
    const float* A_log  = (const float*)d_in[7];
    const float* Dw     = (const float*)d_in[8];
    const float* W_out  = (const float*)d_in[9];
    const float* b_out  = (const float*)d_in[10];
    float* out = (float*)d_out;

    ushort* u    = (ushort*)d_ws;
    ushort* xinb = u;                           // 4,194,304 u
    ushort* resb = xinb + 4194304;              // 4,194,304 u
    ushort* xcb  = resb + 4194304;              // 4,194,304 u
    ushort* Sbf  = xcb + 4194304;               // 2,097,152 u
    ushort* xbf  = Sbf + 2097152;               // 2,097,152 u
    ushort* Wt1  = xbf + 2097152;               // 1,048,576 u
    ushort* Wt2  = Wt1 + 1048576;               //   524,288 u
    ushort* Wxt  = Wt2 + 524288;                //    49,152 u
    ushort* ybf  = Wxt + 49152;                 // 4,194,304 u
    float* scal  = (float*)(ybf + 4194304);     //   196,608 f
    float* RP    = scal + 196608;               //     2,048 f
    float* P     = RP + 2048;                   //   786,432 f

    // 0. all input casts
    prep_all<<<2624, 256, 0, stream>>>(x, W_in, W_out, W_x, xbf, Wt1, Wt2, Wxt);

    // 1. [xinb | resb] = x @ W_in + b_in
    gemm1_mfma<<<dim3(2048 / 128, 4096 / 128), 256, 0, stream>>>(
        xbf, Wt1, b_in, xinb, resb, 4096, 2048, 512);

    // 2. xcb = bf16(silu(conv(xinb)))
    conv_silu<<<(NBATCH * L_SEQ * DI) / 256, 256, 0, stream>>>(xinb, conv_w, conv_b, xcb);

    // 3. GEMM3 partials (B, C, dt)
    gemm3_mfma<<<dim3(4, 4096 / 64), 256, 0, stream>>>(xcb, Wxt, P);

    // 4. rates (blocks 0-1) + B/C reduce (blocks 2-513), one launch
    rates_fused<<<514, 256, 0, stream>>>(P, b_x, scal, A_log, RP);

    // 5-7. fine-chunked scan (separate launches — kernel boundary IS the
    // cheap grid barrier on this chip; see r9 note)
    scan_states<<<dim3(DI / 128, NC, NBATCH), 128, 0, stream>>>(scal, xcb, Sbf);
    stitch<<<dim3(64, NBATCH), 256, 0, stream>>>(Sbf, RP);
    scan_out<<<dim3(DI / 128, NC, NBATCH), 128, 0, stream>>>(scal, xcb, Sbf, Dw, resb, ybf);

    // 8. out = y_act @ W_out + b_out
    gemm2_mfma<<<dim3(512 / 64, 4096 / 128), 256, 0, stream>>>(
        ybf, Wt2, b_out, out, 4096, 512, 1024);
}

// Round 11
// 109.654 us; speedup vs baseline: 3.4241x; 1.1019x over previous
//
#include <hip/hip_runtime.h>
#include <hip/hip_bf16.h>
#include <cmath>

// ---------------------------------------------------------------------------
// Mamba block, round 11: r8 measured-best structure + conv⊗gemm3 fusion.
//   prep_all -> gemm1 -> conv_gemm3 -> reduce8 -> rates_par
//   -> scan_states -> stitch -> scan_out -> gemm2          (9 launches)
//   B=2, L=2048, D_MODEL=512, D_INNER=1024, D_STATE=16, D_CONV=4, EPS=1e-8
// r9 lesson: grid.sync() costs ~100µs+ at this footprint (cross-XCD flush);
// kernel boundaries are the cheap grid barrier.
// r10 lesson: rates_fused measured +4.7 vs split (r8) — keep split.
// ---------------------------------------------------------------------------

#define L_SEQ 2048
#define NBATCH 2
#define DI 1024
#define NC 64
#define LC 32
#define EPS_F 1e-8f
#define LOG_EPS -18.420680744f

typedef __attribute__((ext_vector_type(8))) __bf16 bf16x8;
typedef __attribute__((ext_vector_type(4))) float f32x4;

__device__ __forceinline__ float silu_f(float v) {
    return v / (1.f + __expf(-v));
}

__device__ __forceinline__ ushort bf16_bits(float v) {
    __hip_bfloat16 h = __float2bfloat16(v);
    return *reinterpret_cast<ushort*>(&h);
}

__device__ __forceinline__ float bf2f(ushort u) {
    union { unsigned u; float f; } c;
    c.u = ((unsigned)u) << 16;
    return c.f;
}

// ---------------- GEMM1: [xinb | resb] = x @ W_in^T + b (bf16 out) ---------
__global__ __launch_bounds__(256) void gemm1_mfma(
    const ushort* __restrict__ A, const ushort* __restrict__ Bt,
    const float* __restrict__ bias, ushort* __restrict__ C0,
    ushort* __restrict__ C1, int M, int N, int K)
{
    __shared__ ushort lA[128 * 64];
    __shared__ ushort lB[128 * 64];
    const int tid = threadIdx.x;
    const int w = tid >> 6, ln = tid & 63;
    const int wr = w >> 1, wc = w & 1;
    const int bm = blockIdx.y * 128, bn = blockIdx.x * 128;
    const int q = ln >> 4, r = ln & 15;
    f32x4 acc[4][4] = {};

    for (int k0 = 0; k0 < K; k0 += 64) {
        #pragma unroll
        for (int j = 0; j < 4; ++j) {
            int i = (w * 4 + j) * 64 + ln;
            int m = i >> 3, k8 = (i & 7) * 8;
            __builtin_amdgcn_global_load_lds(
                (const __attribute__((address_space(1))) void*)(A + (size_t)(bm + m) * K + k0 + k8),
                (__attribute__((address_space(3))) void*)(lA + (size_t)i * 8),
                16, 0, 0);
            __builtin_amdgcn_global_load_lds(
                (const __attribute__((address_space(1))) void*)(Bt + (size_t)(bn + m) * K + k0 + k8),
                (__attribute__((address_space(3))) void*)(lB + (size_t)i * 8),
                16, 0, 0);
        }
        __syncthreads();
        #pragma unroll
        for (int kk = 0; kk < 2; ++kk) {
            const int ko = kk * 32 + q * 8;
            bf16x8 af[4], bfr[4];
            #pragma unroll
            for (int m = 0; m < 4; ++m)
                af[m] = *reinterpret_cast<const bf16x8*>(&lA[(wr * 64 + m * 16 + r) * 64 + ko]);
            #pragma unroll
            for (int n = 0; n < 4; ++n)
                bfr[n] = *reinterpret_cast<const bf16x8*>(&lB[(wc * 64 + n * 16 + r) * 64 + ko]);
            #pragma unroll
            for (int m = 0; m < 4; ++m)
                #pragma unroll
                for (int n = 0; n < 4; ++n)
                    acc[m][n] = __builtin_amdgcn_mfma_f32_16x16x32_bf16(af[m], bfr[n], acc[m][n], 0, 0, 0);
        }
        __syncthreads();
    }

    const bool lo = (bn < 1024);
    #pragma unroll
    for (int n = 0; n < 4; ++n) {
        int col = bn + wc * 64 + n * 16 + r;
        float bv = bias[col];
        #pragma unroll
        for (int m = 0; m < 4; ++m) {
            int row0 = bm + wr * 64 + m * 16 + q * 4;
            #pragma unroll
            for (int j = 0; j < 4; ++j) {
                ushort v = bf16_bits(acc[m][n][j] + bv);
                if (lo) C0[(size_t)(row0 + j) * 1024 + col] = v;
                else    C1[(size_t)(row0 + j) * 1024 + (col - 1024)] = v;
            }
        }
    }
}

// ---------------- GEMM2: out = ybf @ Wt2^T + b (f32 out, 128x64 tile) ------
__global__ __launch_bounds__(256) void gemm2_mfma(
    const ushort* __restrict__ A, const ushort* __restrict__ Bt,
    const float* __restrict__ bias, float* __restrict__ C,
    int M, int N, int K)
{
    __shared__ ushort lA[128 * 64];
    __shared__ ushort lB[64 * 64];
    const int tid = threadIdx.x;
    const int w = tid >> 6, ln = tid & 63;
    const int wr = w >> 1, wc = w & 1;
    const int bm = blockIdx.y * 128, bn = blockIdx.x * 64;
    const int q = ln >> 4, r = ln & 15;
    f32x4 acc[4][2] = {};

    for (int k0 = 0; k0 < K; k0 += 64) {
        #pragma unroll
        for (int j = 0; j < 4; ++j) {
            int i = (w * 4 + j) * 64 + ln;
            int m = i >> 3, k8 = (i & 7) * 8;
            __builtin_amdgcn_global_load_lds(
                (const __attribute__((address_space(1))) void*)(A + (size_t)(bm + m) * K + k0 + k8),
                (__attribute__((address_space(3))) void*)(lA + (size_t)i * 8),
                16, 0, 0);
        }
        #pragma unroll
        for (int j = 0; j < 2; ++j) {
            int i = (w * 2 + j) * 64 + ln;
            int m = i >> 3, k8 = (i & 7) * 8;
            __builtin_amdgcn_global_load_lds(
                (const __attribute__((address_space(1))) void*)(Bt + (size_t)(bn + m) * K + k0 + k8),
                (__attribute__((address_space(3))) void*)(lB + (size_t)i * 8),
                16, 0, 0);
        }
        __syncthreads();
        #pragma unroll
        for (int kk = 0; kk < 2; ++kk) {
            const int ko = kk * 32 + q * 8;
            bf16x8 af[4], bfr[2];
            #pragma unroll
            for (int m = 0; m < 4; ++m)
                af[m] = *reinterpret_cast<const bf16x8*>(&lA[(wr * 64 + m * 16 + r) * 64 + ko]);
            #pragma unroll
            for (int n = 0; n < 2; ++n)
                bfr[n] = *reinterpret_cast<const bf16x8*>(&lB[(wc * 32 + n * 16 + r) * 64 + ko]);
            #pragma unroll
            for (int m = 0; m < 4; ++m)
                #pragma unroll
                for (int n = 0; n < 2; ++n)
                    acc[m][n] = __builtin_amdgcn_mfma_f32_16x16x32_bf16(af[m], bfr[n], acc[m][n], 0, 0, 0);
        }
        __syncthreads();
    }

    #pragma unroll
    for (int n = 0; n < 2; ++n) {
        int col = bn + wc * 32 + n * 16 + r;
        float bv = bias[col];
        #pragma unroll
        for (int m = 0; m < 4; ++m) {
            int row0 = bm + wr * 64 + m * 16 + q * 4;
            #pragma unroll
            for (int j = 0; j < 4; ++j)
                C[(size_t)(row0 + j) * N + col] = acc[m][n][j] + bv;
        }
    }
}

// ---------------- fused conv+SiLU + GEMM3 partials -------------------------
// Grid (8 ks, 64 rowtiles), 256 threads. Block: 64 rows x 128-k slice.
// Stage xinb rows [bm-3, bm+64) x [kb, kb+128); conv+SiLU (identical order
// to the old conv_silu); bf16 -> LDS + xcb; MFMA vs Wxt 48-col panel;
// write P[ks] f32 partials. Each (row,d) conv'd exactly once.
__global__ __launch_bounds__(256) void conv_gemm3(
    const ushort* __restrict__ xinb, const float* __restrict__ cw,
    const float* __restrict__ cb, const ushort* __restrict__ Wxt,
    ushort* __restrict__ xcb, float* __restrict__ P)
{
    __shared__ ushort sxin[67 * 128];   // 34,304 B
    __shared__ ushort sxc[64 * 128];    // 16,384 B
    __shared__ ushort swx[48 * 128];    // 12,288 B
    __shared__ float  scw[128][4];      //  2,048 B
    __shared__ float  scb[128];         //    512 B   (total 65,536 B)

    const int t = threadIdx.x;
    const int ks = blockIdx.x, rt = blockIdx.y;
    const int bm = rt * 64;             // global row
    const int kb = ks * 128;            // k/d offset
    const int l0 = bm & (L_SEQ - 1);    // within-batch row

    // stage xinb halo tile (zero rows before batch start)
    for (int i = t; i < 67 * 16; i += 256) {
        int rr = i >> 4, c8 = (i & 15) * 8;
        uint4 v = {0, 0, 0, 0};
        if (l0 + rr - 3 >= 0)
            v = *reinterpret_cast<const uint4*>(&xinb[(size_t)(bm + rr - 3) * 1024 + kb + c8]);
        *reinterpret_cast<uint4*>(&sxin[rr * 128 + c8]) = v;
    }
    // stage Wxt panel 48 x 128
    for (int i = t; i < 48 * 16; i += 256) {
        int rr = i >> 4, c8 = (i & 15) * 8;
        *reinterpret_cast<uint4*>(&swx[rr * 128 + c8]) =
            *reinterpret_cast<const uint4*>(&Wxt[(size_t)rr * 1024 + kb + c8]);
    }
    // conv params
    for (int i = t; i < 512; i += 256) scw[i >> 2][i & 3] = cw[(size_t)(kb + (i >> 2)) * 4 + (i & 3)];
    if (t < 128) scb[t] = cb[kb + t];
    __syncthreads();

    // conv + SiLU: 64 rows x 16 col8-chunks = 1024 chunks, 4 per thread
    for (int i = t; i < 1024; i += 256) {
        int row = i >> 4, c8 = (i & 15) * 8;
        ushort ov[8];
        #pragma unroll
        for (int j = 0; j < 8; ++j) {
            int col = c8 + j;
            float a = scb[col];
            a = fmaf(bf2f(sxin[(row + 0) * 128 + col]), scw[col][0], a);
            a = fmaf(bf2f(sxin[(row + 1) * 128 + col]), scw[col][1], a);
            a = fmaf(bf2f(sxin[(row + 2) * 128 + col]), scw[col][2], a);
            a = fmaf(bf2f(sxin[(row + 3) * 128 + col]), scw[col][3], a);
            ov[j] = bf16_bits(silu_f(a));
        }
        *reinterpret_cast<uint4*>(&sxc[row * 128 + c8]) = *reinterpret_cast<uint4*>(ov);
        *reinterpret_cast<uint4*>(&xcb[(size_t)(bm + row) * 1024 + kb + c8]) =
            *reinterpret_cast<uint4*>(ov);
    }
    __syncthreads();

    // MFMA: wave w owns rows w*16..+16; 3 col-frags x 4 k-slices of 32
    const int w = t >> 6, ln = t & 63;
    const int q = ln >> 4, r = ln & 15;
    f32x4 acc[3] = {};
    #pragma unroll
    for (int kk = 0; kk < 4; ++kk) {
        const int ko = kk * 32 + q * 8;
        bf16x8 af = *reinterpret_cast<const bf16x8*>(&sxc[(w * 16 + r) * 128 + ko]);
        #pragma unroll
        for (int n = 0; n < 3; ++n) {
            bf16x8 bf = *reinterpret_cast<const bf16x8*>(&swx[(n * 16 + r) * 128 + ko]);
            acc[n] = __builtin_amdgcn_mfma_f32_16x16x32_bf16(af, bf, acc[n], 0, 0, 0);
        }
    }

    const int row0 = bm + w * 16 + q * 4;
    const size_t base = (size_t)ks * 196608;
    #pragma unroll
    for (int n = 0; n < 3; ++n)
        #pragma unroll
        for (int j = 0; j < 4; ++j)
            P[base + (size_t)(row0 + j) * 48 + n * 16 + r] = acc[n][j];
}

// ---------------- GEMM3 reduce: scal[l][c] = b_x[c] + sum_ks P (c<33) ------
__global__ __launch_bounds__(256) void gemm3_reduce(
    const float* __restrict__ P, const float* __restrict__ b_x,
    float* __restrict__ scal)
{
    int idx = blockIdx.x * 256 + threadIdx.x;     // < 196608
    int l = idx / 48, c = idx - l * 48;
    if (c >= 33) return;
    float v = b_x[c];
    #pragma unroll
    for (int k = 0; k < 8; ++k) v += P[idx + k * 196608];
    scal[(size_t)l * 48 + c] = v;
}

// ---------------- prep: all input casts in one launch ----------------------
__global__ __launch_bounds__(256) void prep_all(
    const float* __restrict__ x, const float* __restrict__ W_in,
    const float* __restrict__ W_out, const float* __restrict__ W_x,
    ushort* __restrict__ xbf, ushort* __restrict__ Wt1,
    ushort* __restrict__ Wt2, ushort* __restrict__ Wxt)
{
    const int bid = blockIdx.x;
    const int t = threadIdx.x;
    if (bid < 2048) {
        int i = bid * 256 + t;
        float4 v = reinterpret_cast<const float4*>(x)[i];
        ushort4 o;
        o.x = bf16_bits(v.x); o.y = bf16_bits(v.y);
        o.z = bf16_bits(v.z); o.w = bf16_bits(v.w);
        reinterpret_cast<ushort4*>(xbf)[i] = o;
        return;
    }
    if (bid >= 2432) {
        int idx = (bid - 2432) * 256 + t;            // < 49152
        int c = idx >> 10, k = idx & 1023;
        Wxt[idx] = (c < 33) ? bf16_bits(W_x[(size_t)k * 33 + c]) : (ushort)0;
        return;
    }
    __shared__ float ld[64][65];
    const float* src; ushort* dst; int R, C, tile;
    if (bid < 2304) { src = W_in;  dst = Wt1; R = 512;  C = 2048; tile = bid - 2048; }
    else            { src = W_out; dst = Wt2; R = 1024; C = 512;  tile = bid - 2304; }
    const int ctiles = C / 64;
    const int r0 = (tile / ctiles) * 64, c0 = (tile % ctiles) * 64;
    #pragma unroll
    for (int i = 0; i < 16; ++i) {
        int idx = t + i * 256;
        int rr = idx >> 6, cc = idx & 63;
        ld[rr][cc] = src[(size_t)(r0 + rr) * C + c0 + cc];
    }
    __syncthreads();
    #pragma unroll
    for (int i = 0; i < 16; ++i) {
        int idx = t + i * 256;
        int cc = idx >> 6, rr = idx & 63;
        dst[(size_t)(c0 + cc) * R + r0 + rr] = bf16_bits(ld[rr][cc]);
    }
}

// ---------------- parallel rates via log-space scan (NC=64) ----------------
__global__ __launch_bounds__(256) void rates_par(
    float* __restrict__ scal, const float* __restrict__ A_log,
    float* __restrict__ RP)
{
    int b = blockIdx.x;
    int t = threadIdx.x;
    __shared__ float cdt[L_SEQ];
    __shared__ float wsum[4];
    __shared__ float An[16];
    if (t < 16) An[t] = -__expf(A_log[t]);
    float* base = scal + (long)b * L_SEQ * 48;

    float dt[8];
    float run = 0.f;
    const int l0 = t * 8;
    #pragma unroll
    for (int i = 0; i < 8; ++i) {
        float raw = base[(l0 + i) * 48 + 32];
        float d = (raw > 20.f) ? raw : log1pf(__expf(raw));
        dt[i] = d;
        run += d;
        cdt[l0 + i] = run;
    }

    float x = run;
    int lane = t & 63;
    #pragma unroll
    for (int d = 1; d < 64; d <<= 1) {
        float v = __shfl_up(x, d, 64);
        if (lane >= d) x += v;
    }
    int w = t >> 6;
    if (lane == 63) wsum[w] = x;
    __syncthreads();
    float woff = 0.f;
    for (int i = 0; i < w; ++i) woff += wsum[i];
    float toff = woff + x - run;
    #pragma unroll
    for (int i = 0; i < 8; ++i) cdt[l0 + i] += toff;
    __syncthreads();

    float cprev = (l0 == 0) ? 0.f : cdt[l0 - 1];
    #pragma unroll
    for (int i = 0; i < 8; ++i) {
        int l = l0 + i;
        float cl = cdt[l];
        float rv[16];
        #pragma unroll
        for (int s = 0; s < 16; ++s) {
            float A = An[s];
            float rr;
            if (A * cl >= LOG_EPS) {
                rr = __expf(A * dt[i]);
            } else {
                float lp = A * cprev;
                rr = (lp >= LOG_EPS) ? EPS_F / __expf(lp) : 1.f;
            }
            rv[s] = rr;
        }
        float4* dst = reinterpret_cast<float4*>(base + l * 48 + 32);
        dst[0] = *reinterpret_cast<float4*>(&rv[0]);
        dst[1] = *reinterpret_cast<float4*>(&rv[4]);
        dst[2] = *reinterpret_cast<float4*>(&rv[8]);
        dst[3] = *reinterpret_cast<float4*>(&rv[12]);
        cprev = cl;
    }

    if ((t & 3) == 3) {
        int c = t >> 2;
        float ce = cdt[c * LC + LC - 1];
        float cp = (c == 0) ? 0.f : cdt[c * LC - 1];
        for (int s = 0; s < 16; ++s) {
            float A = An[s];
            float pe = fmaxf(__expf(A * ce), EPS_F);
            float pp = fmaxf(__expf(A * cp), EPS_F);
            RP[(b * NC + c) * 16 + s] = pe / pp;
        }
    }
}

// ---------------- phase A: per-chunk local end states (bf16 in/out) --------
__global__ __launch_bounds__(128) void scan_states(
    const float* __restrict__ scal, const ushort* __restrict__ xcb,
    ushort* __restrict__ Sbf)
{
    int b = blockIdx.z, c = blockIdx.y;
    int d = blockIdx.x * 128 + threadIdx.x;
    __shared__ float sc[LC * 48];
    const float4* src = reinterpret_cast<const float4*>(scal + ((long)(b * L_SEQ) + c * LC) * 48);
    float4* dst = reinterpret_cast<float4*>(sc);
    for (int i = threadIdx.x; i < LC * 48 / 4; i += 128) dst[i] = src[i];

    const ushort* xcp = xcb + ((long)(b * L_SEQ) + c * LC) * 1024 + d;
    float xv[LC];
    #pragma unroll
    for (int ll = 0; ll < LC; ++ll) xv[ll] = bf2f(xcp[(long)ll * 1024]);
    __syncthreads();

    float h[16];
    #pragma unroll
    for (int s = 0; s < 16; ++s) h[s] = 0.f;
    #pragma unroll
    for (int ll = 0; ll < LC; ++ll) {
        const float* e = sc + ll * 48;
        #pragma unroll
        for (int s = 0; s < 16; ++s) h[s] = fmaf(e[32 + s], h[s], e[s] * xv[ll]);
    }
    ushort* Sp = Sbf + ((long)(b * NC + c) * 16) * 1024 + d;
    #pragma unroll
    for (int s = 0; s < 16; ++s) Sp[(long)s * 1024] = bf16_bits(h[s]);
}

// ---------------- stitch (in-place, batched) --------------------------------
__global__ __launch_bounds__(256) void stitch(
    ushort* __restrict__ Sbf, const float* __restrict__ RP)
{
    const int tid = threadIdx.x;
    const int idx = blockIdx.x * 256 + tid;
    const int b = blockIdx.y;
    const int d = idx & 1023, s = idx >> 10;
    __shared__ float rps[NC];
    if (tid < NC) rps[tid] = RP[(b * NC + tid) * 16 + s];

    const long base = ((long)(b * NC) * 16 + s) * 1024 + d;
    const long cs = 16 * 1024;
    float v[NC];
    #pragma unroll
    for (int c = 0; c < NC; ++c) v[c] = bf2f(Sbf[base + c * cs]);
    __syncthreads();
    float H = 0.f;
    #pragma unroll
    for (int c = 0; c < NC; ++c) {
        float tmp = v[c];
        v[c] = H;
        H = fmaf(rps[c], H, tmp);
    }
    #pragma unroll
    for (int c = 0; c < NC; ++c) Sbf[base + c * cs] = bf16_bits(v[c]);
}

// ---------------- phase B: full scan + y + gating -> bf16 ------------------
__global__ __launch_bounds__(128) void scan_out(
    const float* __restrict__ scal, const ushort* __restrict__ xcb,
    const ushort* __restrict__ Hin, const float* __restrict__ Dw,
    const ushort* __restrict__ resb, ushort* __restrict__ ybf)
{
    int b = blockIdx.z, c = blockIdx.y;
    int d = blockIdx.x * 128 + threadIdx.x;
    __shared__ float sc[LC * 48];
    const float4* src = reinterpret_cast<const float4*>(scal + ((long)(b * L_SEQ) + c * LC) * 48);
    float4* dst = reinterpret_cast<float4*>(sc);
    for (int i = threadIdx.x; i < LC * 48 / 4; i += 128) dst[i] = src[i];

    const long row0 = (long)(b * L_SEQ) + c * LC;
    float xv[LC], rv[LC];
    #pragma unroll
    for (int ll = 0; ll < LC; ++ll) xv[ll] = bf2f(xcb[(row0 + ll) * 1024 + d]);
    #pragma unroll
    for (int ll = 0; ll < LC; ++ll) rv[ll] = bf2f(resb[(row0 + ll) * 1024 + d]);
    float h[16];
    long hoff = ((long)(b * NC + c) * 16) * 1024 + d;
    #pragma unroll
    for (int s = 0; s < 16; ++s) h[s] = bf2f(Hin[hoff + (long)s * 1024]);
    __syncthreads();

    float Dd = Dw[d];
    #pragma unroll
    for (int ll = 0; ll < LC; ++ll) {
        const float* e = sc + ll * 48;
        float y = 0.f;
        #pragma unroll
        for (int s = 0; s < 16; ++s) {
            h[s] = fmaf(e[32 + s], h[s], e[s] * xv[ll]);
            y = fmaf(e[16 + s], h[s], y);
        }
        y = fmaf(Dd, xv[ll], y);
        ybf[(row0 + ll) * 1024 + d] = bf16_bits(y * silu_f(rv[ll]));
    }
}

// ---------------------------------------------------------------------------
extern "C" void kernel_launch(void* const* d_in, const int* in_sizes, int n_in,
                              void* d_out, int out_size, void* d_ws, size_t ws_size,
                              hipStream_t stream)
{
    const float* x      = (const float*)d_in[0];
    const float* W_in   = (const float*)d_in[1];
    const float* b_in   = (const float*)d_in[2];
    const float* conv_w = (const float*)d_in[3];
    const float* conv_b = (const float*)d_in[4];
    const float* W_x    = (const float*)d_in[5];
    const float* b_x    = (const float*)d_in[6];
    const float* A_log  = (const float*)d_in[7];
    const float* Dw     = (const float*)d_in[8];
    const float* W_out  = (const float*)d_in[9];
    const float* b_out  = (const float*)d_in[10];
    float* out = (float*)d_out;

    ushort* u    = (ushort*)d_ws;
    ushort* xinb = u;                           // 4,194,304 u
    ushort* resb = xinb + 4194304;              // 4,194,304 u
    ushort* xcb  = resb + 4194304;              // 4,194,304 u
    ushort* Sbf  = xcb + 4194304;               // 2,097,152 u
    ushort* xbf  = Sbf + 2097152;               // 2,097,152 u
    ushort* Wt1  = xbf + 2097152;               // 1,048,576 u
    ushort* Wt2  = Wt1 + 1048576;               //   524,288 u
    ushort* Wxt  = Wt2 + 524288;                //    49,152 u
    ushort* ybf  = Wxt + 49152;                 // 4,194,304 u
    float* scal  = (float*)(ybf + 4194304);     //   196,608 f
    float* RP    = scal + 196608;               //     2,048 f
    float* P     = RP + 2048;                   // 1,572,864 f (8 partials)

    // 0. all input casts
    prep_all<<<2624, 256, 0, stream>>>(x, W_in, W_out, W_x, xbf, Wt1, Wt2, Wxt);

    // 1. [xinb | resb] = x @ W_in + b_in
    gemm1_mfma<<<dim3(2048 / 128, 4096 / 128), 256, 0, stream>>>(
        xbf, Wt1, b_in, xinb, resb, 4096, 2048, 512);

    // 2. fused conv+SiLU -> xcb and GEMM3 partials (B, C, dt) -> P
    conv_gemm3<<<dim3(8, 64), 256, 0, stream>>>(xinb, conv_w, conv_b, Wxt, xcb, P);

    // 3. reduce partials -> scal cols 0..32
    gemm3_reduce<<<768, 256, 0, stream>>>(P, b_x, scal);

    // 4. parallel log-space rates
    rates_par<<<NBATCH, 256, 0, stream>>>(scal, A_log, RP);

    // 5-7. fine-chunked scan (separate launches — kernel boundary IS the
    // cheap grid barrier on this chip; see r9 note)
    scan_states<<<dim3(DI / 128, NC, NBATCH), 128, 0, stream>>>(scal, xcb, Sbf);
    stitch<<<dim3(64, NBATCH), 256, 0, stream>>>(Sbf, RP);
    scan_out<<<dim3(DI / 128, NC, NBATCH), 128, 0, stream>>>(scal, xcb, Sbf, Dw, resb, ybf);

    // 8. out = y_act @ W_out + b_out
    gemm2_mfma<<<dim3(512 / 64, 4096 / 128), 256, 0, stream>>>(
        ybf, Wt2, b_out, out, 4096, 512, 1024);
}

// Round 12
// 102.229 us; speedup vs baseline: 3.6728x; 1.0726x over previous
//
#include <hip/hip_runtime.h>
#include <hip/hip_bf16.h>
#include <cmath>

// ---------------------------------------------------------------------------
// Mamba block, round 12: r11 + rates inlined into scans.
//   prep_all -> gemm1 -> conv_gemm3 -> reduce(528) -> rates_scan(2 blk, tiny)
//   -> scan_states -> stitch -> scan_out -> gemm2          (9 launches)
//   B=2, L=2048, D_MODEL=512, D_INNER=1024, D_STATE=16, D_CONV=4, EPS=1e-8
// r9 lesson: grid.sync() ~100µs+ at this footprint; kernel boundaries are the
// cheap grid barrier. r10: merged rates+reduce regressed; keep rates separate.
// r11: fusion OK only when >=1 block/CU survives.
// ---------------------------------------------------------------------------

#define L_SEQ 2048
#define NBATCH 2
#define DI 1024
#define NC 64
#define LC 32
#define EPS_F 1e-8f
#define LOG_EPS -18.420680744f

typedef __attribute__((ext_vector_type(8))) __bf16 bf16x8;
typedef __attribute__((ext_vector_type(4))) float f32x4;

__device__ __forceinline__ float silu_f(float v) {
    return v / (1.f + __expf(-v));
}

__device__ __forceinline__ ushort bf16_bits(float v) {
    __hip_bfloat16 h = __float2bfloat16(v);
    return *reinterpret_cast<ushort*>(&h);
}

__device__ __forceinline__ float bf2f(ushort u) {
    union { unsigned u; float f; } c;
    c.u = ((unsigned)u) << 16;
    return c.f;
}

// rate for state s at in-batch row l: identical formula to the old rates_par.
__device__ __forceinline__ float rate_of(float A, float dl, float cl, float cp) {
    if (A * cl >= LOG_EPS) return __expf(A * dl);
    float lp = A * cp;
    return (lp >= LOG_EPS) ? EPS_F / __expf(lp) : 1.f;
}

// ---------------- GEMM1: [xinb | resb] = x @ W_in^T + b (bf16 out) ---------
__global__ __launch_bounds__(256) void gemm1_mfma(
    const ushort* __restrict__ A, const ushort* __restrict__ Bt,
    const float* __restrict__ bias, ushort* __restrict__ C0,
    ushort* __restrict__ C1, int M, int N, int K)
{
    __shared__ ushort lA[128 * 64];
    __shared__ ushort lB[128 * 64];
    const int tid = threadIdx.x;
    const int w = tid >> 6, ln = tid & 63;
    const int wr = w >> 1, wc = w & 1;
    const int bm = blockIdx.y * 128, bn = blockIdx.x * 128;
    const int q = ln >> 4, r = ln & 15;
    f32x4 acc[4][4] = {};

    for (int k0 = 0; k0 < K; k0 += 64) {
        #pragma unroll
        for (int j = 0; j < 4; ++j) {
            int i = (w * 4 + j) * 64 + ln;
            int m = i >> 3, k8 = (i & 7) * 8;
            __builtin_amdgcn_global_load_lds(
                (const __attribute__((address_space(1))) void*)(A + (size_t)(bm + m) * K + k0 + k8),
                (__attribute__((address_space(3))) void*)(lA + (size_t)i * 8),
                16, 0, 0);
            __builtin_amdgcn_global_load_lds(
                (const __attribute__((address_space(1))) void*)(Bt + (size_t)(bn + m) * K + k0 + k8),
                (__attribute__((address_space(3))) void*)(lB + (size_t)i * 8),
                16, 0, 0);
        }
        __syncthreads();
        #pragma unroll
        for (int kk = 0; kk < 2; ++kk) {
            const int ko = kk * 32 + q * 8;
            bf16x8 af[4], bfr[4];
            #pragma unroll
            for (int m = 0; m < 4; ++m)
                af[m] = *reinterpret_cast<const bf16x8*>(&lA[(wr * 64 + m * 16 + r) * 64 + ko]);
            #pragma unroll
            for (int n = 0; n < 4; ++n)
                bfr[n] = *reinterpret_cast<const bf16x8*>(&lB[(wc * 64 + n * 16 + r) * 64 + ko]);
            #pragma unroll
            for (int m = 0; m < 4; ++m)
                #pragma unroll
                for (int n = 0; n < 4; ++n)
                    acc[m][n] = __builtin_amdgcn_mfma_f32_16x16x32_bf16(af[m], bfr[n], acc[m][n], 0, 0, 0);
        }
        __syncthreads();
    }

    const bool lo = (bn < 1024);
    #pragma unroll
    for (int n = 0; n < 4; ++n) {
        int col = bn + wc * 64 + n * 16 + r;
        float bv = bias[col];
        #pragma unroll
        for (int m = 0; m < 4; ++m) {
            int row0 = bm + wr * 64 + m * 16 + q * 4;
            #pragma unroll
            for (int j = 0; j < 4; ++j) {
                ushort v = bf16_bits(acc[m][n][j] + bv);
                if (lo) C0[(size_t)(row0 + j) * 1024 + col] = v;
                else    C1[(size_t)(row0 + j) * 1024 + (col - 1024)] = v;
            }
        }
    }
}

// ---------------- GEMM2: out = ybf @ Wt2^T + b (f32 out, 128x64 tile) ------
__global__ __launch_bounds__(256) void gemm2_mfma(
    const ushort* __restrict__ A, const ushort* __restrict__ Bt,
    const float* __restrict__ bias, float* __restrict__ C,
    int M, int N, int K)
{
    __shared__ ushort lA[128 * 64];
    __shared__ ushort lB[64 * 64];
    const int tid = threadIdx.x;
    const int w = tid >> 6, ln = tid & 63;
    const int wr = w >> 1, wc = w & 1;
    const int bm = blockIdx.y * 128, bn = blockIdx.x * 64;
    const int q = ln >> 4, r = ln & 15;
    f32x4 acc[4][2] = {};

    for (int k0 = 0; k0 < K; k0 += 64) {
        #pragma unroll
        for (int j = 0; j < 4; ++j) {
            int i = (w * 4 + j) * 64 + ln;
            int m = i >> 3, k8 = (i & 7) * 8;
            __builtin_amdgcn_global_load_lds(
                (const __attribute__((address_space(1))) void*)(A + (size_t)(bm + m) * K + k0 + k8),
                (__attribute__((address_space(3))) void*)(lA + (size_t)i * 8),
                16, 0, 0);
        }
        #pragma unroll
        for (int j = 0; j < 2; ++j) {
            int i = (w * 2 + j) * 64 + ln;
            int m = i >> 3, k8 = (i & 7) * 8;
            __builtin_amdgcn_global_load_lds(
                (const __attribute__((address_space(1))) void*)(Bt + (size_t)(bn + m) * K + k0 + k8),
                (__attribute__((address_space(3))) void*)(lB + (size_t)i * 8),
                16, 0, 0);
        }
        __syncthreads();
        #pragma unroll
        for (int kk = 0; kk < 2; ++kk) {
            const int ko = kk * 32 + q * 8;
            bf16x8 af[4], bfr[2];
            #pragma unroll
            for (int m = 0; m < 4; ++m)
                af[m] = *reinterpret_cast<const bf16x8*>(&lA[(wr * 64 + m * 16 + r) * 64 + ko]);
            #pragma unroll
            for (int n = 0; n < 2; ++n)
                bfr[n] = *reinterpret_cast<const bf16x8*>(&lB[(wc * 32 + n * 16 + r) * 64 + ko]);
            #pragma unroll
            for (int m = 0; m < 4; ++m)
                #pragma unroll
                for (int n = 0; n < 2; ++n)
                    acc[m][n] = __builtin_amdgcn_mfma_f32_16x16x32_bf16(af[m], bfr[n], acc[m][n], 0, 0, 0);
        }
        __syncthreads();
    }

    #pragma unroll
    for (int n = 0; n < 2; ++n) {
        int col = bn + wc * 32 + n * 16 + r;
        float bv = bias[col];
        #pragma unroll
        for (int m = 0; m < 4; ++m) {
            int row0 = bm + wr * 64 + m * 16 + q * 4;
            #pragma unroll
            for (int j = 0; j < 4; ++j)
                C[(size_t)(row0 + j) * N + col] = acc[m][n][j] + bv;
        }
    }
}

// ---------------- fused conv+SiLU + GEMM3 partials -------------------------
__global__ __launch_bounds__(256) void conv_gemm3(
    const ushort* __restrict__ xinb, const float* __restrict__ cw,
    const float* __restrict__ cb, const ushort* __restrict__ Wxt,
    ushort* __restrict__ xcb, float* __restrict__ P)
{
    __shared__ ushort sxin[67 * 128];
    __shared__ ushort sxc[64 * 128];
    __shared__ ushort swx[48 * 128];
    __shared__ float  scw[128][4];
    __shared__ float  scb[128];

    const int t = threadIdx.x;
    const int ks = blockIdx.x, rt = blockIdx.y;
    const int bm = rt * 64;
    const int kb = ks * 128;
    const int l0 = bm & (L_SEQ - 1);

    for (int i = t; i < 67 * 16; i += 256) {
        int rr = i >> 4, c8 = (i & 15) * 8;
        uint4 v = {0, 0, 0, 0};
        if (l0 + rr - 3 >= 0)
            v = *reinterpret_cast<const uint4*>(&xinb[(size_t)(bm + rr - 3) * 1024 + kb + c8]);
        *reinterpret_cast<uint4*>(&sxin[rr * 128 + c8]) = v;
    }
    for (int i = t; i < 48 * 16; i += 256) {
        int rr = i >> 4, c8 = (i & 15) * 8;
        *reinterpret_cast<uint4*>(&swx[rr * 128 + c8]) =
            *reinterpret_cast<const uint4*>(&Wxt[(size_t)rr * 1024 + kb + c8]);
    }
    for (int i = t; i < 512; i += 256) scw[i >> 2][i & 3] = cw[(size_t)(kb + (i >> 2)) * 4 + (i & 3)];
    if (t < 128) scb[t] = cb[kb + t];
    __syncthreads();

    for (int i = t; i < 1024; i += 256) {
        int row = i >> 4, c8 = (i & 15) * 8;
        ushort ov[8];
        #pragma unroll
        for (int j = 0; j < 8; ++j) {
            int col = c8 + j;
            float a = scb[col];
            a = fmaf(bf2f(sxin[(row + 0) * 128 + col]), scw[col][0], a);
            a = fmaf(bf2f(sxin[(row + 1) * 128 + col]), scw[col][1], a);
            a = fmaf(bf2f(sxin[(row + 2) * 128 + col]), scw[col][2], a);
            a = fmaf(bf2f(sxin[(row + 3) * 128 + col]), scw[col][3], a);
            ov[j] = bf16_bits(silu_f(a));
        }
        *reinterpret_cast<uint4*>(&sxc[row * 128 + c8]) = *reinterpret_cast<uint4*>(ov);
        *reinterpret_cast<uint4*>(&xcb[(size_t)(bm + row) * 1024 + kb + c8]) =
            *reinterpret_cast<uint4*>(ov);
    }
    __syncthreads();

    const int w = t >> 6, ln = t & 63;
    const int q = ln >> 4, r = ln & 15;
    f32x4 acc[3] = {};
    #pragma unroll
    for (int kk = 0; kk < 4; ++kk) {
        const int ko = kk * 32 + q * 8;
        bf16x8 af = *reinterpret_cast<const bf16x8*>(&sxc[(w * 16 + r) * 128 + ko]);
        #pragma unroll
        for (int n = 0; n < 3; ++n) {
            bf16x8 bf = *reinterpret_cast<const bf16x8*>(&swx[(n * 16 + r) * 128 + ko]);
            acc[n] = __builtin_amdgcn_mfma_f32_16x16x32_bf16(af, bf, acc[n], 0, 0, 0);
        }
    }

    const int row0 = bm + w * 16 + q * 4;
    const size_t base = (size_t)ks * 196608;
    #pragma unroll
    for (int n = 0; n < 3; ++n)
        #pragma unroll
        for (int j = 0; j < 4; ++j)
            P[base + (size_t)(row0 + j) * 48 + n * 16 + r] = acc[n][j];
}

// ---------------- GEMM3 reduce: B/C -> scal32, raw dt -> dtr ---------------
// bid < 512 : scal32[l][c] = b_x[c] + sum_ks P[ks][l][c]   (c < 32)
// bid >= 512: dtr[l]       = b_x[32] + sum_ks P[ks][l][32]
__global__ __launch_bounds__(256) void gemm3_reduce(
    const float* __restrict__ P, const float* __restrict__ b_x,
    float* __restrict__ scal32, float* __restrict__ dtr)
{
    const int bid = blockIdx.x;
    if (bid < 512) {
        int idx = bid * 256 + threadIdx.x;        // < 131072
        int l = idx >> 5, c = idx & 31;
        int pi = l * 48 + c;
        float v = b_x[c];
        #pragma unroll
        for (int k = 0; k < 8; ++k) v += P[pi + k * 196608];
        scal32[idx] = v;
    } else {
        int l = (bid - 512) * 256 + threadIdx.x;  // < 4096
        int pi = l * 48 + 32;
        float v = b_x[32];
        #pragma unroll
        for (int k = 0; k < 8; ++k) v += P[pi + k * 196608];
        dtr[l] = v;
    }
}

// ---------------- prep: all input casts in one launch ----------------------
__global__ __launch_bounds__(256) void prep_all(
    const float* __restrict__ x, const float* __restrict__ W_in,
    const float* __restrict__ W_out, const float* __restrict__ W_x,
    ushort* __restrict__ xbf, ushort* __restrict__ Wt1,
    ushort* __restrict__ Wt2, ushort* __restrict__ Wxt)
{
    const int bid = blockIdx.x;
    const int t = threadIdx.x;
    if (bid < 2048) {
        int i = bid * 256 + t;
        float4 v = reinterpret_cast<const float4*>(x)[i];
        ushort4 o;
        o.x = bf16_bits(v.x); o.y = bf16_bits(v.y);
        o.z = bf16_bits(v.z); o.w = bf16_bits(v.w);
        reinterpret_cast<ushort4*>(xbf)[i] = o;
        return;
    }
    if (bid >= 2432) {
        int idx = (bid - 2432) * 256 + t;            // < 49152
        int c = idx >> 10, k = idx & 1023;
        Wxt[idx] = (c < 33) ? bf16_bits(W_x[(size_t)k * 33 + c]) : (ushort)0;
        return;
    }
    __shared__ float ld[64][65];
    const float* src; ushort* dst; int R, C, tile;
    if (bid < 2304) { src = W_in;  dst = Wt1; R = 512;  C = 2048; tile = bid - 2048; }
    else            { src = W_out; dst = Wt2; R = 1024; C = 512;  tile = bid - 2304; }
    const int ctiles = C / 64;
    const int r0 = (tile / ctiles) * 64, c0 = (tile % ctiles) * 64;
    #pragma unroll
    for (int i = 0; i < 16; ++i) {
        int idx = t + i * 256;
        int rr = idx >> 6, cc = idx & 63;
        ld[rr][cc] = src[(size_t)(r0 + rr) * C + c0 + cc];
    }
    __syncthreads();
    #pragma unroll
    for (int i = 0; i < 16; ++i) {
        int idx = t + i * 256;
        int cc = idx >> 6, rr = idx & 63;
        dst[(size_t)(c0 + cc) * R + r0 + rr] = bf16_bits(ld[rr][cc]);
    }
}

// ---------------- rates scan: softplus + cumsum + RP (tiny) ----------------
// One block of 256 per batch. Reads dtr; writes dtv (dt), dtc (cumsum), RP.
__global__ __launch_bounds__(256) void rates_scan(
    const float* __restrict__ dtr, const float* __restrict__ A_log,
    float* __restrict__ dtv, float* __restrict__ dtc, float* __restrict__ RP)
{
    int b = blockIdx.x;
    int t = threadIdx.x;
    __shared__ float cdt[L_SEQ];
    __shared__ float wsum[4];
    __shared__ float An[16];
    if (t < 16) An[t] = -__expf(A_log[t]);
    const float* dr = dtr + (size_t)b * L_SEQ;

    float dt[8];
    float run = 0.f;
    const int l0 = t * 8;
    #pragma unroll
    for (int i = 0; i < 8; ++i) {
        float raw = dr[l0 + i];
        float d = (raw > 20.f) ? raw : log1pf(__expf(raw));
        dt[i] = d;
        run += d;
        cdt[l0 + i] = run;
    }

    float x = run;
    int lane = t & 63;
    #pragma unroll
    for (int d = 1; d < 64; d <<= 1) {
        float v = __shfl_up(x, d, 64);
        if (lane >= d) x += v;
    }
    int w = t >> 6;
    if (lane == 63) wsum[w] = x;
    __syncthreads();
    float woff = 0.f;
    for (int i = 0; i < w; ++i) woff += wsum[i];
    float toff = woff + x - run;
    #pragma unroll
    for (int i = 0; i < 8; ++i) cdt[l0 + i] += toff;
    __syncthreads();

    // write dt and cumsum
    float cv[8];
    #pragma unroll
    for (int i = 0; i < 8; ++i) cv[i] = cdt[l0 + i];
    float4* dv = reinterpret_cast<float4*>(dtv + (size_t)b * L_SEQ + l0);
    float4* dc = reinterpret_cast<float4*>(dtc + (size_t)b * L_SEQ + l0);
    dv[0] = *reinterpret_cast<float4*>(&dt[0]);
    dv[1] = *reinterpret_cast<float4*>(&dt[4]);
    dc[0] = *reinterpret_cast<float4*>(&cv[0]);
    dc[1] = *reinterpret_cast<float4*>(&cv[4]);

    // per-chunk rate products (chunk = 32 steps; thread 4c+3 owns chunk c)
    if ((t & 3) == 3) {
        int c = t >> 2;
        float ce = cdt[c * LC + LC - 1];
        float cp = (c == 0) ? 0.f : cdt[c * LC - 1];
        for (int s = 0; s < 16; ++s) {
            float A = An[s];
            float pe = fmaxf(__expf(A * ce), EPS_F);
            float pp = fmaxf(__expf(A * cp), EPS_F);
            RP[(b * NC + c) * 16 + s] = pe / pp;
        }
    }
}

// ---------------- phase A: chunk states; rates computed in-block -----------
__global__ __launch_bounds__(128) void scan_states(
    const float* __restrict__ scal32, const float* __restrict__ dtv,
    const float* __restrict__ dtc, const float* __restrict__ A_log,
    const ushort* __restrict__ xcb, ushort* __restrict__ Sbf)
{
    int b = blockIdx.z, c = blockIdx.y;
    int d = blockIdx.x * 128 + threadIdx.x;
    const int t = threadIdx.x;
    __shared__ float sbc[LC * 32];
    __shared__ float srt[LC][16];
    __shared__ float An[16];

    const float4* src = reinterpret_cast<const float4*>(scal32 + ((size_t)(b * L_SEQ) + c * LC) * 32);
    float4* dst = reinterpret_cast<float4*>(sbc);
    for (int i = t; i < LC * 32 / 4; i += 128) dst[i] = src[i];
    if (t < 16) An[t] = -__expf(A_log[t]);

    const ushort* xcp = xcb + ((size_t)(b * L_SEQ) + c * LC) * 1024 + d;
    float xv[LC];
    #pragma unroll
    for (int ll = 0; ll < LC; ++ll) xv[ll] = bf2f(xcp[(size_t)ll * 1024]);
    __syncthreads();

    // in-block rates: 32 rows x 16 states, 4 per thread (formula == rates_par)
    {
        const int gb = b * L_SEQ + c * LC;
        #pragma unroll
        for (int k = 0; k < 4; ++k) {
            int idx = t * 4 + k;
            int l = idx >> 4, s = idx & 15;
            float cl = dtc[gb + l];
            float dl = dtv[gb + l];
            float cp = (c == 0 && l == 0) ? 0.f : dtc[gb + l - 1];
            srt[l][s] = rate_of(An[s], dl, cl, cp);
        }
    }
    __syncthreads();

    float h[16];
    #pragma unroll
    for (int s = 0; s < 16; ++s) h[s] = 0.f;
    #pragma unroll
    for (int ll = 0; ll < LC; ++ll) {
        const float* e = sbc + ll * 32;
        #pragma unroll
        for (int s = 0; s < 16; ++s) h[s] = fmaf(srt[ll][s], h[s], e[s] * xv[ll]);
    }
    ushort* Sp = Sbf + ((size_t)(b * NC + c) * 16) * 1024 + d;
    #pragma unroll
    for (int s = 0; s < 16; ++s) Sp[(size_t)s * 1024] = bf16_bits(h[s]);
}

// ---------------- stitch (in-place, batched) --------------------------------
__global__ __launch_bounds__(256) void stitch(
    ushort* __restrict__ Sbf, const float* __restrict__ RP)
{
    const int tid = threadIdx.x;
    const int idx = blockIdx.x * 256 + tid;
    const int b = blockIdx.y;
    const int d = idx & 1023, s = idx >> 10;
    __shared__ float rps[NC];
    if (tid < NC) rps[tid] = RP[(b * NC + tid) * 16 + s];

    const long base = ((long)(b * NC) * 16 + s) * 1024 + d;
    const long cs = 16 * 1024;
    float v[NC];
    #pragma unroll
    for (int c = 0; c < NC; ++c) v[c] = bf2f(Sbf[base + c * cs]);
    __syncthreads();
    float H = 0.f;
    #pragma unroll
    for (int c = 0; c < NC; ++c) {
        float tmp = v[c];
        v[c] = H;
        H = fmaf(rps[c], H, tmp);
    }
    #pragma unroll
    for (int c = 0; c < NC; ++c) Sbf[base + c * cs] = bf16_bits(v[c]);
}

// ---------------- phase B: full scan + y + gating -> bf16 ------------------
__global__ __launch_bounds__(128) void scan_out(
    const float* __restrict__ scal32, const float* __restrict__ dtv,
    const float* __restrict__ dtc, const float* __restrict__ A_log,
    const ushort* __restrict__ xcb, const ushort* __restrict__ Hin,
    const float* __restrict__ Dw, const ushort* __restrict__ resb,
    ushort* __restrict__ ybf)
{
    int b = blockIdx.z, c = blockIdx.y;
    int d = blockIdx.x * 128 + threadIdx.x;
    const int t = threadIdx.x;
    __shared__ float sbc[LC * 32];
    __shared__ float srt[LC][16];
    __shared__ float An[16];

    const float4* src = reinterpret_cast<const float4*>(scal32 + ((size_t)(b * L_SEQ) + c * LC) * 32);
    float4* dst = reinterpret_cast<float4*>(sbc);
    for (int i = t; i < LC * 32 / 4; i += 128) dst[i] = src[i];
    if (t < 16) An[t] = -__expf(A_log[t]);

    const long row0 = (long)(b * L_SEQ) + c * LC;
    float xv[LC], rv[LC];
    #pragma unroll
    for (int ll = 0; ll < LC; ++ll) xv[ll] = bf2f(xcb[(row0 + ll) * 1024 + d]);
    #pragma unroll
    for (int ll = 0; ll < LC; ++ll) rv[ll] = bf2f(resb[(row0 + ll) * 1024 + d]);
    float h[16];
    long hoff = ((long)(b * NC + c) * 16) * 1024 + d;
    #pragma unroll
    for (int s = 0; s < 16; ++s) h[s] = bf2f(Hin[hoff + (long)s * 1024]);
    __syncthreads();

    {
        const int gb = b * L_SEQ + c * LC;
        #pragma unroll
        for (int k = 0; k < 4; ++k) {
            int idx = t * 4 + k;
            int l = idx >> 4, s = idx & 15;
            float cl = dtc[gb + l];
            float dl = dtv[gb + l];
            float cp = (c == 0 && l == 0) ? 0.f : dtc[gb + l - 1];
            srt[l][s] = rate_of(An[s], dl, cl, cp);
        }
    }
    __syncthreads();

    float Dd = Dw[d];
    #pragma unroll
    for (int ll = 0; ll < LC; ++ll) {
        const float* e = sbc + ll * 32;
        float y = 0.f;
        #pragma unroll
        for (int s = 0; s < 16; ++s) {
            h[s] = fmaf(srt[ll][s], h[s], e[s] * xv[ll]);
            y = fmaf(e[16 + s], h[s], y);
        }
        y = fmaf(Dd, xv[ll], y);
        ybf[(row0 + ll) * 1024 + d] = bf16_bits(y * silu_f(rv[ll]));
    }
}

// ---------------------------------------------------------------------------
extern "C" void kernel_launch(void* const* d_in, const int* in_sizes, int n_in,
                              void* d_out, int out_size, void* d_ws, size_t ws_size,
                              hipStream_t stream)
{
    const float* x      = (const float*)d_in[0];
    const float* W_in   = (const float*)d_in[1];
    const float* b_in   = (const float*)d_in[2];
    const float* conv_w = (const float*)d_in[3];
    const float* conv_b = (const float*)d_in[4];
    const float* W_x    = (const float*)d_in[5];
    const float* b_x    = (const float*)d_in[6];
    const float* A_log  = (const float*)d_in[7];
    const float* Dw     = (const float*)d_in[8];
    const float* W_out  = (const float*)d_in[9];
    const float* b_out  = (const float*)d_in[10];
    float* out = (float*)d_out;

    ushort* u    = (ushort*)d_ws;
    ushort* xinb = u;                           // 4,194,304 u
    ushort* resb = xinb + 4194304;              // 4,194,304 u
    ushort* xcb  = resb + 4194304;              // 4,194,304 u
    ushort* Sbf  = xcb + 4194304;               // 2,097,152 u
    ushort* xbf  = Sbf + 2097152;               // 2,097,152 u
    ushort* Wt1  = xbf + 2097152;               // 1,048,576 u
    ushort* Wt2  = Wt1 + 1048576;               //   524,288 u
    ushort* Wxt  = Wt2 + 524288;                //    49,152 u
    ushort* ybf  = Wxt + 49152;                 // 4,194,304 u
    float* scal32 = (float*)(ybf + 4194304);    //   131,072 f
    float* dtr   = scal32 + 131072;             //     4,096 f
    float* dtv   = dtr + 4096;                  //     4,096 f
    float* dtc   = dtv + 4096;                  //     4,096 f
    float* RP    = dtc + 4096;                  //     2,048 f
    float* P     = RP + 2048;                   // 1,572,864 f

    // 0. all input casts
    prep_all<<<2624, 256, 0, stream>>>(x, W_in, W_out, W_x, xbf, Wt1, Wt2, Wxt);

    // 1. [xinb | resb] = x @ W_in + b_in
    gemm1_mfma<<<dim3(2048 / 128, 4096 / 128), 256, 0, stream>>>(
        xbf, Wt1, b_in, xinb, resb, 4096, 2048, 512);

    // 2. fused conv+SiLU -> xcb and GEMM3 partials (B, C, dt) -> P
    conv_gemm3<<<dim3(8, 64), 256, 0, stream>>>(xinb, conv_w, conv_b, Wxt, xcb, P);

    // 3. reduce partials -> scal32 (B,C) + dtr (raw dt)
    gemm3_reduce<<<528, 256, 0, stream>>>(P, b_x, scal32, dtr);

    // 4. tiny rate scan: softplus + cumsum + RP
    rates_scan<<<NBATCH, 256, 0, stream>>>(dtr, A_log, dtv, dtc, RP);

    // 5-7. fine-chunked scan, rates computed in-block (bit-identical formula)
    scan_states<<<dim3(DI / 128, NC, NBATCH), 128, 0, stream>>>(
        scal32, dtv, dtc, A_log, xcb, Sbf);
    stitch<<<dim3(64, NBATCH), 256, 0, stream>>>(Sbf, RP);
    scan_out<<<dim3(DI / 128, NC, NBATCH), 128, 0, stream>>>(
        scal32, dtv, dtc, A_log, xcb, Sbf, Dw, resb, ybf);

    // 8. out = y_act @ W_out + b_out
    gemm2_mfma<<<dim3(512 / 64, 4096 / 128), 256, 0, stream>>>(
        ybf, Wt2, b_out, out, 4096, 512, 1024);
}